// Round 4
// baseline (401.501 us; speedup 1.0000x reference)
//
#include <hip/hip_runtime.h>

typedef unsigned int uint;
typedef unsigned short ushort_t;
typedef short bf16x8 __attribute__((ext_vector_type(8)));
typedef float f32x4 __attribute__((ext_vector_type(4)));

// ---------- bf16 helpers ----------
__device__ __forceinline__ ushort_t f2bf(float f) {
  uint u = __builtin_bit_cast(uint, f);
  u += 0x7fffu + ((u >> 16) & 1u);
  return (ushort_t)(u >> 16);
}
__device__ __forceinline__ float bf2f(ushort_t s) {
  return __builtin_bit_cast(float, (uint)s << 16);
}
__device__ __forceinline__ bf16x8 ld_frag(const ushort_t* p) {
  return __builtin_bit_cast(bf16x8, *(const uint4*)p);
}

// ---------- Kernel 1: depthwise conv 3x3 s2 p1 + LayerNorm -> bf16 ----------
__global__ __launch_bounds__(384) void k_convln(
    const float* __restrict__ x, const float* __restrict__ wc,
    const float* __restrict__ g, const float* __restrict__ bb,
    ushort_t* __restrict__ qout)
{
  const int b  = blockIdx.x / 784;
  const int t  = blockIdx.x % 784;
  const int oy = t / 28, ox = t % 28;
  const int c  = threadIdx.x;
  const float* xb = x + (size_t)b * 3136 * 384 + c;
  float acc = 0.f;
  #pragma unroll
  for (int ky = 0; ky < 3; ky++) {
    const int iy = 2 * oy - 1 + ky;
    if (iy < 0 || iy >= 56) continue;
    #pragma unroll
    for (int kx = 0; kx < 3; kx++) {
      const int ix = 2 * ox - 1 + kx;
      if (ix < 0 || ix >= 56) continue;
      acc += wc[c * 9 + ky * 3 + kx] * xb[(size_t)(iy * 56 + ix) * 384];
    }
  }
  float s = acc, s2 = acc * acc;
  #pragma unroll
  for (int off = 32; off >= 1; off >>= 1) {
    s  += __shfl_xor(s,  off);
    s2 += __shfl_xor(s2, off);
  }
  __shared__ float ps[6], ps2[6];
  if ((c & 63) == 0) { ps[c >> 6] = s; ps2[c >> 6] = s2; }
  __syncthreads();
  float S = 0.f, S2 = 0.f;
  #pragma unroll
  for (int i = 0; i < 6; i++) { S += ps[i]; S2 += ps2[i]; }
  const float mu  = S * (1.f / 384.f);
  const float var = S2 * (1.f / 384.f) - mu * mu;
  const float inv = rsqrtf(var + 1e-5f);
  qout[((size_t)b * 784 + t) * 384 + c] = f2bf((acc - mu) * inv * g[c] + bb[c]);
}

// ---------- Kernel 2: 2x2 average pool -> bf16 ----------
__global__ __launch_bounds__(256) void k_pool(
    const float* __restrict__ x, ushort_t* __restrict__ kvout)
{
  const int idx = blockIdx.x * 256 + threadIdx.x;
  const int c = idx % 384;
  const int t = (idx / 384) % 784;
  const int b = idx / (384 * 784);
  const int ty = t / 28, tx = t % 28;
  const float* xb = x + (size_t)b * 3136 * 384 + c;
  const int r0 = (2 * ty) * 56 + 2 * tx;
  const float v = xb[(size_t)r0 * 384] + xb[(size_t)(r0 + 1) * 384]
                + xb[(size_t)(r0 + 56) * 384] + xb[(size_t)(r0 + 57) * 384];
  kvout[idx] = f2bf(v * 0.25f);
}

// ---------- Kernel 3: weights f32 -> bf16 ----------
__global__ __launch_bounds__(256) void k_wcvt(
    const float* __restrict__ a, const float* __restrict__ b,
    const float* __restrict__ c, const float* __restrict__ d,
    ushort_t* __restrict__ oa, ushort_t* __restrict__ ob,
    ushort_t* __restrict__ oc, ushort_t* __restrict__ od)
{
  const int i = blockIdx.x * 256 + threadIdx.x;
  if (i < 147456) {
    oa[i] = f2bf(a[i]); ob[i] = f2bf(b[i]);
    oc[i] = f2bf(c[i]); od[i] = f2bf(d[i]);
  }
}

// ---------- Kernel 4: dense MFMA GEMM, M=6272 N=384 K=384 ----------
template<int MODE>
__global__ __launch_bounds__(256) void k_gemm(
    const ushort_t* __restrict__ X, const ushort_t* __restrict__ W,
    const float* __restrict__ bias, void* __restrict__ Y)
{
  __shared__ ushort_t As[128][40];
  __shared__ ushort_t Bs[128][40];
  const int tid = threadIdx.x, w = tid >> 6, lane = tid & 63;
  const int quad = lane >> 4, r = lane & 15;
  const int m0 = blockIdx.y * 128, n0 = blockIdx.x * 128;
  const int wm = w >> 1, wn = w & 1;
  const int lr = tid >> 2, lc = (tid & 3) << 3;
  const ushort_t* xp = X + (size_t)(m0 + lr) * 384 + lc;
  const ushort_t* wp = W + (size_t)(n0 + lr) * 384 + lc;
  f32x4 acc[4][4] = {};
  for (int k0 = 0; k0 < 384; k0 += 32) {
    __syncthreads();
    *(uint4*)&As[lr][lc]      = *(const uint4*)(xp + k0);
    *(uint4*)&As[lr + 64][lc] = *(const uint4*)(xp + (size_t)64 * 384 + k0);
    *(uint4*)&Bs[lr][lc]      = *(const uint4*)(wp + k0);
    *(uint4*)&Bs[lr + 64][lc] = *(const uint4*)(wp + (size_t)64 * 384 + k0);
    __syncthreads();
    bf16x8 af[4], bf_[4];
    #pragma unroll
    for (int mt = 0; mt < 4; mt++) af[mt]  = *(const bf16x8*)&As[wm * 64 + mt * 16 + r][quad * 8];
    #pragma unroll
    for (int nt = 0; nt < 4; nt++) bf_[nt] = *(const bf16x8*)&Bs[wn * 64 + nt * 16 + r][quad * 8];
    #pragma unroll
    for (int mt = 0; mt < 4; mt++)
      #pragma unroll
      for (int nt = 0; nt < 4; nt++)
        acc[mt][nt] = __builtin_amdgcn_mfma_f32_16x16x32_bf16(af[mt], bf_[nt], acc[mt][nt], 0, 0, 0);
  }
  #pragma unroll
  for (int mt = 0; mt < 4; mt++) {
    #pragma unroll
    for (int nt = 0; nt < 4; nt++) {
      #pragma unroll
      for (int i = 0; i < 4; i++) {
        const int row = m0 + wm * 64 + mt * 16 + quad * 4 + i;
        const int col = n0 + wn * 64 + nt * 16 + r;
        const float v = acc[mt][nt][i];
        if constexpr (MODE == 2) {
          ((float*)Y)[(size_t)row * 384 + col] = v + bias[col];
        } else if constexpr (MODE == 0) {
          ((ushort_t*)Y)[(size_t)row * 384 + col] = f2bf(v);
        } else {
          const int bb = row / 784, tt = row % 784;
          ((ushort_t*)Y)[((size_t)bb * 384 + col) * 784 + tt] = f2bf(v);
        }
      }
    }
  }
}

// ---------- Kernel 5: fused flash attention w/ head-mix + bilinear residual --
// One WG (256 thr, 4 waves) per (b, 16-row l-tile). 13 t-tiles of 64.
// A: QK^T MFMA (all 6 heads) -> S LDS (f32, scaled)
// B: fuse + online softmax -> P LDS (bf16), alpha/m/s state
// C: PV MFMA, O accumulator rescale by alpha
__global__ __launch_bounds__(256) void k_fattn(
    const ushort_t* __restrict__ Qb, const ushort_t* __restrict__ Kb,
    const ushort_t* __restrict__ Vt, const float* __restrict__ ra,
    const float* __restrict__ w_fuse, const float* __restrict__ b_fuse,
    ushort_t* __restrict__ O)
{
  __shared__ float    Ssc[6][16][68];   // 26112 B, pad 64->68 (16B-aligned rows)
  __shared__ ushort_t Pl[6][16][72];    // 13824 B, pad 64->72 (144B rows, 16B-aligned)
  __shared__ float m_st[6][16], s_st[6][16], a_st[6][16];
  __shared__ float wf[72], bfu[6];

  const int tid  = threadIdx.x;
  const int w    = tid >> 6, lane = tid & 63;
  const int quad = lane >> 4, r = lane & 15;
  const int b    = blockIdx.x & 7;          // XCD-affine batch mapping
  const int m0   = (blockIdx.x >> 3) * 16;

  if (tid < 72) wf[tid] = w_fuse[tid];
  if (tid < 6)  bfu[tid] = b_fuse[tid];
  if (tid < 96) { (&m_st[0][0])[tid] = -1e30f; (&s_st[0][0])[tid] = 0.f; }

  // persistent Q A-fragments (row l = m0 + r, all 6 heads x 2 k-steps)
  const ushort_t* qrow = Qb + ((size_t)(b * 784 + m0 + r)) * 384 + quad * 8;
  bf16x8 qf[6][2];
  #pragma unroll
  for (int h = 0; h < 6; h++) {
    qf[h][0] = ld_frag(qrow + h * 64);
    qf[h][1] = ld_frag(qrow + h * 64 + 32);
  }

  // phase-B per-thread constants: thread = (l = tid>>4, 4 t's at tq*4)
  const int bl_l = tid >> 4, tq = tid & 15;
  const int L = m0 + bl_l;
  const int Yc = L / 28, Xc = L % 28;
  const float cy = fminf(fmaxf((float)Yc * 0.5f - 0.25f, 0.f), 13.f);
  const float cx = fminf(fmaxf((float)Xc * 0.5f - 0.25f, 0.f), 13.f);
  const int y0 = (int)cy, y1 = min(y0 + 1, 13);
  const int x0 = (int)cx, x1 = min(x0 + 1, 13);
  const float fy = cy - (float)y0, fx = cx - (float)x0;
  const float w00 = (1.f - fy) * (1.f - fx), w01 = (1.f - fy) * fx;
  const float w10 = fy * (1.f - fx),         w11 = fy * fx;
  const int p00 = (y0 * 14 + x0) * 784, p01 = (y0 * 14 + x1) * 784;
  const int p10 = (y1 * 14 + x0) * 784, p11 = (y1 * 14 + x1) * 784;
  const float* rab = ra + (size_t)b * 6 * 196 * 784;

  const size_t kbase  = (size_t)b * 784 * 384;
  const size_t vtbase = (size_t)b * 384 * 784;
  const float scale = 0.05103103630798288f; // 384^-0.5

  f32x4 oacc[6] = {};   // wave w holds (o=0..5, d-subtile = w)

  for (int it = 0; it < 13; it++) {
    const int t0 = it * 64;

    // ---- phase A: QK^T for t-subtile w ----
    {
      const int tA = min(t0 + w * 16 + r, 783);
      const ushort_t* krow = Kb + kbase + (size_t)tA * 384 + quad * 8;
      #pragma unroll
      for (int h = 0; h < 6; h++) {
        f32x4 sc = {};
        sc = __builtin_amdgcn_mfma_f32_16x16x32_bf16(qf[h][0], ld_frag(krow + h * 64),      sc, 0, 0, 0);
        sc = __builtin_amdgcn_mfma_f32_16x16x32_bf16(qf[h][1], ld_frag(krow + h * 64 + 32), sc, 0, 0, 0);
        #pragma unroll
        for (int i = 0; i < 4; i++)
          Ssc[h][quad * 4 + i][w * 16 + r] = sc[i] * scale;
      }
    }
    __syncthreads();

    // ---- phase B: fuse + online softmax ----
    {
      const int t4  = t0 + tq * 4;
      const int t4c = min(t4, 780);
      float4 sv[6], rx[6];
      #pragma unroll
      for (int c = 0; c < 6; c++) sv[c] = *(const float4*)&Ssc[c][bl_l][tq * 4];
      #pragma unroll
      for (int c = 0; c < 6; c++) {
        const float* rc = rab + (size_t)c * 153664 + t4c;
        const float4 a = *(const float4*)(rc + p00);
        const float4 bq = *(const float4*)(rc + p01);
        const float4 cc = *(const float4*)(rc + p10);
        const float4 d = *(const float4*)(rc + p11);
        rx[c].x = w00 * a.x + w01 * bq.x + w10 * cc.x + w11 * d.x;
        rx[c].y = w00 * a.y + w01 * bq.y + w10 * cc.y + w11 * d.y;
        rx[c].z = w00 * a.z + w01 * bq.z + w10 * cc.z + w11 * d.z;
        rx[c].w = w00 * a.w + w01 * bq.w + w10 * cc.w + w11 * d.w;
      }
      float F[6][4];
      #pragma unroll
      for (int o = 0; o < 6; o++) {
        float4 acc4 = {bfu[o], bfu[o], bfu[o], bfu[o]};
        #pragma unroll
        for (int c = 0; c < 6; c++) {
          const float w1 = wf[o * 12 + c], w2 = wf[o * 12 + 6 + c];
          acc4.x += w1 * sv[c].x + w2 * rx[c].x;
          acc4.y += w1 * sv[c].y + w2 * rx[c].y;
          acc4.z += w1 * sv[c].z + w2 * rx[c].z;
          acc4.w += w1 * sv[c].w + w2 * rx[c].w;
        }
        F[o][0] = acc4.x; F[o][1] = acc4.y; F[o][2] = acc4.z; F[o][3] = acc4.w;
      }
      #pragma unroll
      for (int j = 0; j < 4; j++) {
        if (t4 + j >= 784) {
          #pragma unroll
          for (int o = 0; o < 6; o++) F[o][j] = -1e30f;
        }
      }
      #pragma unroll
      for (int o = 0; o < 6; o++) {
        float mx = fmaxf(fmaxf(F[o][0], F[o][1]), fmaxf(F[o][2], F[o][3]));
        #pragma unroll
        for (int off = 8; off >= 1; off >>= 1) mx = fmaxf(mx, __shfl_xor(mx, off));
        const float m_old = m_st[o][bl_l];
        const float nm = fmaxf(m_old, mx);
        const float al = __expf(m_old - nm);
        float p0 = __expf(F[o][0] - nm), p1 = __expf(F[o][1] - nm);
        float p2 = __expf(F[o][2] - nm), p3 = __expf(F[o][3] - nm);
        float sm = p0 + p1 + p2 + p3;
        #pragma unroll
        for (int off = 8; off >= 1; off >>= 1) sm += __shfl_xor(sm, off);
        const uint lo = (uint)f2bf(p0) | ((uint)f2bf(p1) << 16);
        const uint hi = (uint)f2bf(p2) | ((uint)f2bf(p3) << 16);
        *(uint2*)&Pl[o][bl_l][tq * 4] = uint2{lo, hi};
        if (tq == 0) {
          m_st[o][bl_l] = nm;
          s_st[o][bl_l] = s_st[o][bl_l] * al + sm;
          a_st[o][bl_l] = al;
        }
      }
    }
    __syncthreads();

    // ---- phase C: O = O*alpha + P.V (d-subtile w) ----
    #pragma unroll
    for (int o = 0; o < 6; o++) {
      const f32x4 al4 = *(const f32x4*)&a_st[o][quad * 4];
      oacc[o] *= al4;
      const bf16x8 pa0 = *(const bf16x8*)&Pl[o][r][quad * 8];
      const bf16x8 pa1 = *(const bf16x8*)&Pl[o][r][quad * 8 + 32];
      const ushort_t* vrow = Vt + vtbase + (size_t)(o * 64 + w * 16 + r) * 784 + t0 + quad * 8;
      oacc[o] = __builtin_amdgcn_mfma_f32_16x16x32_bf16(pa0, ld_frag(vrow),      oacc[o], 0, 0, 0);
      oacc[o] = __builtin_amdgcn_mfma_f32_16x16x32_bf16(pa1, ld_frag(vrow + 32), oacc[o], 0, 0, 0);
    }
  }

  // ---- epilogue: normalize by row sums, write bf16 ----
  #pragma unroll
  for (int o = 0; o < 6; o++) {
    const f32x4 s4 = *(const f32x4*)&s_st[o][quad * 4];
    #pragma unroll
    for (int i = 0; i < 4; i++) {
      const int row = b * 784 + m0 + quad * 4 + i;
      O[(size_t)row * 384 + o * 64 + w * 16 + r] = f2bf(oacc[o][i] / s4[i]);
    }
  }
}

// ---------- host launcher ----------
extern "C" void kernel_launch(void* const* d_in, const int* in_sizes, int n_in,
                              void* d_out, int out_size, void* d_ws, size_t ws_size,
                              hipStream_t stream)
{
  const float* x        = (const float*)d_in[0];
  const float* res_attn = (const float*)d_in[1];
  const float* conv_w   = (const float*)d_in[2];
  const float* ln_g     = (const float*)d_in[3];
  const float* ln_b     = (const float*)d_in[4];
  const float* wq       = (const float*)d_in[5];
  const float* wk       = (const float*)d_in[6];
  const float* wv       = (const float*)d_in[7];
  const float* w_proj   = (const float*)d_in[8];
  const float* b_proj   = (const float*)d_in[9];
  const float* w_fuse   = (const float*)d_in[10];
  const float* b_fuse   = (const float*)d_in[11];
  float* out = (float*)d_out;

  const size_t NE = (size_t)8 * 784 * 384;      // 2,408,448
  const size_t NW = 147456;
  ushort_t* q_ln_b = (ushort_t*)d_ws;
  ushort_t* kv_b   = q_ln_b + NE;
  ushort_t* Qb     = kv_b + NE;
  ushort_t* Kb     = Qb + NE;
  ushort_t* Vt     = Kb + NE;   // (b, 384, 784)
  ushort_t* Opre   = Vt + NE;
  ushort_t* wqb    = Opre + NE;
  ushort_t* wkb    = wqb + NW;
  ushort_t* wvb    = wkb + NW;
  ushort_t* wpb    = wvb + NW;

  k_convln<<<dim3(8 * 784), dim3(384), 0, stream>>>(x, conv_w, ln_g, ln_b, q_ln_b);
  k_pool  <<<dim3(9408),    dim3(256), 0, stream>>>(x, kv_b);
  k_wcvt  <<<dim3(576),     dim3(256), 0, stream>>>(wq, wk, wv, w_proj, wqb, wkb, wvb, wpb);

  k_gemm<0><<<dim3(3, 49), dim3(256), 0, stream>>>(q_ln_b, wqb, nullptr, Qb);
  k_gemm<0><<<dim3(3, 49), dim3(256), 0, stream>>>(kv_b,   wkb, nullptr, Kb);
  k_gemm<1><<<dim3(3, 49), dim3(256), 0, stream>>>(kv_b,   wvb, nullptr, Vt);

  k_fattn<<<dim3(392), dim3(256), 0, stream>>>(Qb, Kb, Vt, res_attn, w_fuse, b_fuse, Opre);

  k_gemm<2><<<dim3(3, 49), dim3(256), 0, stream>>>(Opre, wpb, b_proj, out);
}

// Round 5
// 387.332 us; speedup vs baseline: 1.0366x; 1.0366x over previous
//
#include <hip/hip_runtime.h>

typedef unsigned int uint;
typedef unsigned short ushort_t;
typedef short bf16x8 __attribute__((ext_vector_type(8)));
typedef float f32x4 __attribute__((ext_vector_type(4)));

// ---------- bf16 helpers ----------
__device__ __forceinline__ ushort_t f2bf(float f) {
  uint u = __builtin_bit_cast(uint, f);
  u += 0x7fffu + ((u >> 16) & 1u);
  return (ushort_t)(u >> 16);
}
__device__ __forceinline__ float bf2f(ushort_t s) {
  return __builtin_bit_cast(float, (uint)s << 16);
}
__device__ __forceinline__ bf16x8 ld_frag(const ushort_t* p) {
  return __builtin_bit_cast(bf16x8, *(const uint4*)p);
}

// ---------- Kernel 1: depthwise conv 3x3 s2 p1 + LayerNorm -> bf16 ----------
__global__ __launch_bounds__(384) void k_convln(
    const float* __restrict__ x, const float* __restrict__ wc,
    const float* __restrict__ g, const float* __restrict__ bb,
    ushort_t* __restrict__ qout)
{
  const int b  = blockIdx.x / 784;
  const int t  = blockIdx.x % 784;
  const int oy = t / 28, ox = t % 28;
  const int c  = threadIdx.x;
  const float* xb = x + (size_t)b * 3136 * 384 + c;
  float acc = 0.f;
  #pragma unroll
  for (int ky = 0; ky < 3; ky++) {
    const int iy = 2 * oy - 1 + ky;
    if (iy < 0 || iy >= 56) continue;
    #pragma unroll
    for (int kx = 0; kx < 3; kx++) {
      const int ix = 2 * ox - 1 + kx;
      if (ix < 0 || ix >= 56) continue;
      acc += wc[c * 9 + ky * 3 + kx] * xb[(size_t)(iy * 56 + ix) * 384];
    }
  }
  float s = acc, s2 = acc * acc;
  #pragma unroll
  for (int off = 32; off >= 1; off >>= 1) {
    s  += __shfl_xor(s,  off);
    s2 += __shfl_xor(s2, off);
  }
  __shared__ float ps[6], ps2[6];
  if ((c & 63) == 0) { ps[c >> 6] = s; ps2[c >> 6] = s2; }
  __syncthreads();
  float S = 0.f, S2 = 0.f;
  #pragma unroll
  for (int i = 0; i < 6; i++) { S += ps[i]; S2 += ps2[i]; }
  const float mu  = S * (1.f / 384.f);
  const float var = S2 * (1.f / 384.f) - mu * mu;
  const float inv = rsqrtf(var + 1e-5f);
  qout[((size_t)b * 784 + t) * 384 + c] = f2bf((acc - mu) * inv * g[c] + bb[c]);
}

// ---------- Kernel 2: 2x2 average pool -> bf16 ----------
__global__ __launch_bounds__(256) void k_pool(
    const float* __restrict__ x, ushort_t* __restrict__ kvout)
{
  const int idx = blockIdx.x * 256 + threadIdx.x;
  const int c = idx % 384;
  const int t = (idx / 384) % 784;
  const int b = idx / (384 * 784);
  const int ty = t / 28, tx = t % 28;
  const float* xb = x + (size_t)b * 3136 * 384 + c;
  const int r0 = (2 * ty) * 56 + 2 * tx;
  const float v = xb[(size_t)r0 * 384] + xb[(size_t)(r0 + 1) * 384]
                + xb[(size_t)(r0 + 56) * 384] + xb[(size_t)(r0 + 57) * 384];
  kvout[idx] = f2bf(v * 0.25f);
}

// ---------- Kernel 3: weights f32 -> bf16 ----------
__global__ __launch_bounds__(256) void k_wcvt(
    const float* __restrict__ a, const float* __restrict__ b,
    const float* __restrict__ c, const float* __restrict__ d,
    ushort_t* __restrict__ oa, ushort_t* __restrict__ ob,
    ushort_t* __restrict__ oc, ushort_t* __restrict__ od)
{
  const int i = blockIdx.x * 256 + threadIdx.x;
  if (i < 147456) {
    oa[i] = f2bf(a[i]); ob[i] = f2bf(b[i]);
    oc[i] = f2bf(c[i]); od[i] = f2bf(d[i]);
  }
}

// ---------- Kernel 4: dense MFMA GEMM, M=6272 N=384 K=384 ----------
template<int MODE>
__global__ __launch_bounds__(256) void k_gemm(
    const ushort_t* __restrict__ X, const ushort_t* __restrict__ W,
    const float* __restrict__ bias, void* __restrict__ Y)
{
  __shared__ ushort_t As[128][40];
  __shared__ ushort_t Bs[128][40];
  const int tid = threadIdx.x, w = tid >> 6, lane = tid & 63;
  const int quad = lane >> 4, r = lane & 15;
  const int m0 = blockIdx.y * 128, n0 = blockIdx.x * 128;
  const int wm = w >> 1, wn = w & 1;
  const int lr = tid >> 2, lc = (tid & 3) << 3;
  const ushort_t* xp = X + (size_t)(m0 + lr) * 384 + lc;
  const ushort_t* wp = W + (size_t)(n0 + lr) * 384 + lc;
  f32x4 acc[4][4] = {};
  for (int k0 = 0; k0 < 384; k0 += 32) {
    __syncthreads();
    *(uint4*)&As[lr][lc]      = *(const uint4*)(xp + k0);
    *(uint4*)&As[lr + 64][lc] = *(const uint4*)(xp + (size_t)64 * 384 + k0);
    *(uint4*)&Bs[lr][lc]      = *(const uint4*)(wp + k0);
    *(uint4*)&Bs[lr + 64][lc] = *(const uint4*)(wp + (size_t)64 * 384 + k0);
    __syncthreads();
    bf16x8 af[4], bf_[4];
    #pragma unroll
    for (int mt = 0; mt < 4; mt++) af[mt]  = *(const bf16x8*)&As[wm * 64 + mt * 16 + r][quad * 8];
    #pragma unroll
    for (int nt = 0; nt < 4; nt++) bf_[nt] = *(const bf16x8*)&Bs[wn * 64 + nt * 16 + r][quad * 8];
    #pragma unroll
    for (int mt = 0; mt < 4; mt++)
      #pragma unroll
      for (int nt = 0; nt < 4; nt++)
        acc[mt][nt] = __builtin_amdgcn_mfma_f32_16x16x32_bf16(af[mt], bf_[nt], acc[mt][nt], 0, 0, 0);
  }
  #pragma unroll
  for (int mt = 0; mt < 4; mt++) {
    #pragma unroll
    for (int nt = 0; nt < 4; nt++) {
      #pragma unroll
      for (int i = 0; i < 4; i++) {
        const int row = m0 + wm * 64 + mt * 16 + quad * 4 + i;
        const int col = n0 + wn * 64 + nt * 16 + r;
        const float v = acc[mt][nt][i];
        if constexpr (MODE == 2) {
          ((float*)Y)[(size_t)row * 384 + col] = v + bias[col];
        } else if constexpr (MODE == 0) {
          ((ushort_t*)Y)[(size_t)row * 384 + col] = f2bf(v);
        } else {
          const int bb = row / 784, tt = row % 784;
          ((ushort_t*)Y)[((size_t)bb * 384 + col) * 784 + tt] = f2bf(v);
        }
      }
    }
  }
}

// ---------- Kernel 5: fused flash attention, t-split 4-way -----------------
// Grid (392, 4): blockIdx.x -> (b = &7 for XCD affinity, 16-row l-tile),
// blockIdx.y = t-split s. Split s owns t-tiles [tile0, tile0+tileN) of 13.
// Writes UNNORMALIZED O-partial (f32) + per-row (m, s) state; k_comb merges.
__global__ __launch_bounds__(256) void k_fattn(
    const ushort_t* __restrict__ Qb, const ushort_t* __restrict__ Kb,
    const ushort_t* __restrict__ Vt, const float* __restrict__ ra,
    const float* __restrict__ w_fuse, const float* __restrict__ b_fuse,
    float* __restrict__ Op, float* __restrict__ Ms, float* __restrict__ Ss)
{
  __shared__ float    Ssc[6][16][68];   // 26112 B
  __shared__ ushort_t Pl[6][16][72];    // 13824 B
  __shared__ float m_st[6][16], s_st[6][16], a_st[6][16];
  __shared__ float wf[72], bfu[6];

  const int tid  = threadIdx.x;
  const int w    = tid >> 6, lane = tid & 63;
  const int quad = lane >> 4, r = lane & 15;
  const int b    = blockIdx.x & 7;          // XCD-affine batch mapping
  const int m0   = (blockIdx.x >> 3) * 16;
  const int s    = blockIdx.y;
  const int tile0 = (s == 0) ? 0 : (3 * s + 1);  // 0-3 | 4-6 | 7-9 | 10-12
  const int tileN = (s == 0) ? 4 : 3;

  if (tid < 72) wf[tid] = w_fuse[tid];
  if (tid < 6)  bfu[tid] = b_fuse[tid];
  if (tid < 96) { (&m_st[0][0])[tid] = -1e30f; (&s_st[0][0])[tid] = 0.f; }

  // persistent Q A-fragments (row l = m0 + r, all 6 heads x 2 k-steps)
  const ushort_t* qrow = Qb + ((size_t)(b * 784 + m0 + r)) * 384 + quad * 8;
  bf16x8 qf[6][2];
  #pragma unroll
  for (int h = 0; h < 6; h++) {
    qf[h][0] = ld_frag(qrow + h * 64);
    qf[h][1] = ld_frag(qrow + h * 64 + 32);
  }

  // phase-B per-thread constants: thread = (l = tid>>4, 4 t's at tq*4)
  const int bl_l = tid >> 4, tq = tid & 15;
  const int L = m0 + bl_l;
  const int Yc = L / 28, Xc = L % 28;
  const float cy = fminf(fmaxf((float)Yc * 0.5f - 0.25f, 0.f), 13.f);
  const float cx = fminf(fmaxf((float)Xc * 0.5f - 0.25f, 0.f), 13.f);
  const int y0 = (int)cy, y1 = min(y0 + 1, 13);
  const int x0 = (int)cx, x1 = min(x0 + 1, 13);
  const float fy = cy - (float)y0, fx = cx - (float)x0;
  const float w00 = (1.f - fy) * (1.f - fx), w01 = (1.f - fy) * fx;
  const float w10 = fy * (1.f - fx),         w11 = fy * fx;
  const int p00 = (y0 * 14 + x0) * 784, p01 = (y0 * 14 + x1) * 784;
  const int p10 = (y1 * 14 + x0) * 784, p11 = (y1 * 14 + x1) * 784;
  const float* rab = ra + (size_t)b * 6 * 196 * 784;

  const size_t kbase  = (size_t)b * 784 * 384;
  const size_t vtbase = (size_t)b * 384 * 784;
  const float scale = 0.05103103630798288f; // 384^-0.5

  f32x4 oacc[6] = {};   // wave w holds (o=0..5, d-subtile = w)

  for (int ii = 0; ii < tileN; ii++) {
    const int t0 = (tile0 + ii) * 64;

    // ---- phase A: QK^T for t-subtile w ----
    {
      const int tA = min(t0 + w * 16 + r, 783);
      const ushort_t* krow = Kb + kbase + (size_t)tA * 384 + quad * 8;
      #pragma unroll
      for (int h = 0; h < 6; h++) {
        f32x4 sc = {};
        sc = __builtin_amdgcn_mfma_f32_16x16x32_bf16(qf[h][0], ld_frag(krow + h * 64),      sc, 0, 0, 0);
        sc = __builtin_amdgcn_mfma_f32_16x16x32_bf16(qf[h][1], ld_frag(krow + h * 64 + 32), sc, 0, 0, 0);
        #pragma unroll
        for (int i = 0; i < 4; i++)
          Ssc[h][quad * 4 + i][w * 16 + r] = sc[i] * scale;
      }
    }
    __syncthreads();

    // ---- phase B: fuse + online softmax ----
    {
      const int t4  = t0 + tq * 4;
      const int t4c = min(t4, 780);
      float4 sv[6], rx[6];
      #pragma unroll
      for (int c = 0; c < 6; c++) sv[c] = *(const float4*)&Ssc[c][bl_l][tq * 4];
      #pragma unroll
      for (int c = 0; c < 6; c++) {
        const float* rc = rab + (size_t)c * 153664 + t4c;
        const float4 a = *(const float4*)(rc + p00);
        const float4 bq = *(const float4*)(rc + p01);
        const float4 cc = *(const float4*)(rc + p10);
        const float4 d = *(const float4*)(rc + p11);
        rx[c].x = w00 * a.x + w01 * bq.x + w10 * cc.x + w11 * d.x;
        rx[c].y = w00 * a.y + w01 * bq.y + w10 * cc.y + w11 * d.y;
        rx[c].z = w00 * a.z + w01 * bq.z + w10 * cc.z + w11 * d.z;
        rx[c].w = w00 * a.w + w01 * bq.w + w10 * cc.w + w11 * d.w;
      }
      float F[6][4];
      #pragma unroll
      for (int o = 0; o < 6; o++) {
        float4 acc4 = {bfu[o], bfu[o], bfu[o], bfu[o]};
        #pragma unroll
        for (int c = 0; c < 6; c++) {
          const float w1 = wf[o * 12 + c], w2 = wf[o * 12 + 6 + c];
          acc4.x += w1 * sv[c].x + w2 * rx[c].x;
          acc4.y += w1 * sv[c].y + w2 * rx[c].y;
          acc4.z += w1 * sv[c].z + w2 * rx[c].z;
          acc4.w += w1 * sv[c].w + w2 * rx[c].w;
        }
        F[o][0] = acc4.x; F[o][1] = acc4.y; F[o][2] = acc4.z; F[o][3] = acc4.w;
      }
      #pragma unroll
      for (int j = 0; j < 4; j++) {
        if (t4 + j >= 784) {
          #pragma unroll
          for (int o = 0; o < 6; o++) F[o][j] = -1e30f;
        }
      }
      #pragma unroll
      for (int o = 0; o < 6; o++) {
        float mx = fmaxf(fmaxf(F[o][0], F[o][1]), fmaxf(F[o][2], F[o][3]));
        #pragma unroll
        for (int off = 8; off >= 1; off >>= 1) mx = fmaxf(mx, __shfl_xor(mx, off));
        const float m_old = m_st[o][bl_l];
        const float nm = fmaxf(m_old, mx);
        const float al = __expf(m_old - nm);
        float p0 = __expf(F[o][0] - nm), p1 = __expf(F[o][1] - nm);
        float p2 = __expf(F[o][2] - nm), p3 = __expf(F[o][3] - nm);
        float sm = p0 + p1 + p2 + p3;
        #pragma unroll
        for (int off = 8; off >= 1; off >>= 1) sm += __shfl_xor(sm, off);
        const uint lo = (uint)f2bf(p0) | ((uint)f2bf(p1) << 16);
        const uint hi = (uint)f2bf(p2) | ((uint)f2bf(p3) << 16);
        *(uint2*)&Pl[o][bl_l][tq * 4] = uint2{lo, hi};
        if (tq == 0) {
          m_st[o][bl_l] = nm;
          s_st[o][bl_l] = s_st[o][bl_l] * al + sm;
          a_st[o][bl_l] = al;
        }
      }
    }
    __syncthreads();

    // ---- phase C: O = O*alpha + P.V (d-subtile w) ----
    #pragma unroll
    for (int o = 0; o < 6; o++) {
      const f32x4 al4 = *(const f32x4*)&a_st[o][quad * 4];
      oacc[o] *= al4;
      const bf16x8 pa0 = *(const bf16x8*)&Pl[o][r][quad * 8];
      const bf16x8 pa1 = *(const bf16x8*)&Pl[o][r][quad * 8 + 32];
      const ushort_t* vrow = Vt + vtbase + (size_t)(o * 64 + w * 16 + r) * 784 + t0 + quad * 8;
      oacc[o] = __builtin_amdgcn_mfma_f32_16x16x32_bf16(pa0, ld_frag(vrow),      oacc[o], 0, 0, 0);
      oacc[o] = __builtin_amdgcn_mfma_f32_16x16x32_bf16(pa1, ld_frag(vrow + 32), oacc[o], 0, 0, 0);
    }
  }

  // ---- epilogue: write unnormalized partial O + (m,s) state ----
  const size_t prow = (size_t)s * 6272 + (size_t)b * 784 + m0;
  #pragma unroll
  for (int o = 0; o < 6; o++) {
    #pragma unroll
    for (int i = 0; i < 4; i++) {
      Op[(prow + quad * 4 + i) * 384 + o * 64 + w * 16 + r] = oacc[o][i];
    }
  }
  if (tid < 96) {
    const int o = tid >> 4, l = tid & 15;
    Ms[(prow + l) * 6 + o] = m_st[o][l];
    Ss[(prow + l) * 6 + o] = s_st[o][l];
  }
}

// ---------- Kernel 6: combine 4 t-split partials -> normalized bf16 O -------
__global__ __launch_bounds__(256) void k_comb(
    const float* __restrict__ Op, const float* __restrict__ Ms,
    const float* __restrict__ Ss, ushort_t* __restrict__ O)
{
  const int idx = blockIdx.x * 256 + threadIdx.x;   // 2,408,448 total
  const int row = idx / 384, col = idx % 384, o = col >> 6;
  float m = -1e30f;
  #pragma unroll
  for (int s = 0; s < 4; s++) m = fmaxf(m, Ms[((size_t)s * 6272 + row) * 6 + o]);
  float S = 0.f, acc = 0.f;
  #pragma unroll
  for (int s = 0; s < 4; s++) {
    const size_t pr = (size_t)s * 6272 + row;
    const float e = __expf(Ms[pr * 6 + o] - m);
    S   += Ss[pr * 6 + o] * e;
    acc += Op[pr * 384 + col] * e;
  }
  O[(size_t)row * 384 + col] = f2bf(acc / S);
}

// ---------- host launcher ----------
extern "C" void kernel_launch(void* const* d_in, const int* in_sizes, int n_in,
                              void* d_out, int out_size, void* d_ws, size_t ws_size,
                              hipStream_t stream)
{
  const float* x        = (const float*)d_in[0];
  const float* res_attn = (const float*)d_in[1];
  const float* conv_w   = (const float*)d_in[2];
  const float* ln_g     = (const float*)d_in[3];
  const float* ln_b     = (const float*)d_in[4];
  const float* wq       = (const float*)d_in[5];
  const float* wk       = (const float*)d_in[6];
  const float* wv       = (const float*)d_in[7];
  const float* w_proj   = (const float*)d_in[8];
  const float* b_proj   = (const float*)d_in[9];
  const float* w_fuse   = (const float*)d_in[10];
  const float* b_fuse   = (const float*)d_in[11];
  float* out = (float*)d_out;

  const size_t NE = (size_t)8 * 784 * 384;      // 2,408,448
  const size_t NW = 147456;
  ushort_t* q_ln_b = (ushort_t*)d_ws;
  ushort_t* kv_b   = q_ln_b + NE;
  ushort_t* Qb     = kv_b + NE;
  ushort_t* Kb     = Qb + NE;
  ushort_t* Vt     = Kb + NE;        // (b, 384, 784) + 64-elem pad
  ushort_t* Opre   = Vt + NE + 64;
  ushort_t* wqb    = Opre + NE;
  ushort_t* wkb    = wqb + NW;
  ushort_t* wvb    = wkb + NW;
  ushort_t* wpb    = wvb + NW;
  float*    Op     = (float*)(wpb + NW);  // [4][6272][384] f32 = 38.6 MB
  float*    Ms     = Op + 4 * NE;         // [4][6272][6]
  float*    Ss     = Ms + 4 * 6272 * 6;

  k_convln<<<dim3(8 * 784), dim3(384), 0, stream>>>(x, conv_w, ln_g, ln_b, q_ln_b);
  k_pool  <<<dim3(9408),    dim3(256), 0, stream>>>(x, kv_b);
  k_wcvt  <<<dim3(576),     dim3(256), 0, stream>>>(wq, wk, wv, w_proj, wqb, wkb, wvb, wpb);

  k_gemm<0><<<dim3(3, 49), dim3(256), 0, stream>>>(q_ln_b, wqb, nullptr, Qb);
  k_gemm<0><<<dim3(3, 49), dim3(256), 0, stream>>>(kv_b,   wkb, nullptr, Kb);
  k_gemm<1><<<dim3(3, 49), dim3(256), 0, stream>>>(kv_b,   wvb, nullptr, Vt);

  k_fattn<<<dim3(392, 4), dim3(256), 0, stream>>>(Qb, Kb, Vt, res_attn,
                                                  w_fuse, b_fuse, Op, Ms, Ss);
  k_comb <<<dim3(9408),   dim3(256), 0, stream>>>(Op, Ms, Ss, Opre);

  k_gemm<2><<<dim3(3, 49), dim3(256), 0, stream>>>(Opre, wpb, b_proj, out);
}

// Round 6
// 373.396 us; speedup vs baseline: 1.0753x; 1.0373x over previous
//
#include <hip/hip_runtime.h>

typedef unsigned int uint;
typedef unsigned short ushort_t;
typedef short bf16x8 __attribute__((ext_vector_type(8)));
typedef float f32x4 __attribute__((ext_vector_type(4)));

// ---------- bf16 helpers ----------
__device__ __forceinline__ ushort_t f2bf(float f) {
  uint u = __builtin_bit_cast(uint, f);
  u += 0x7fffu + ((u >> 16) & 1u);
  return (ushort_t)(u >> 16);
}
__device__ __forceinline__ float bf2f(ushort_t s) {
  return __builtin_bit_cast(float, (uint)s << 16);
}
__device__ __forceinline__ float bflo(uint u) { return __builtin_bit_cast(float, u << 16); }
__device__ __forceinline__ float bfhi(uint u) { return __builtin_bit_cast(float, u & 0xffff0000u); }
__device__ __forceinline__ bf16x8 ld_frag(const ushort_t* p) {
  return __builtin_bit_cast(bf16x8, *(const uint4*)p);
}

// ---------- Kernel 1: depthwise conv 3x3 s2 p1 + LayerNorm -> bf16 ----------
__global__ __launch_bounds__(384) void k_convln(
    const float* __restrict__ x, const float* __restrict__ wc,
    const float* __restrict__ g, const float* __restrict__ bb,
    ushort_t* __restrict__ qout)
{
  const int b  = blockIdx.x / 784;
  const int t  = blockIdx.x % 784;
  const int oy = t / 28, ox = t % 28;
  const int c  = threadIdx.x;
  const float* xb = x + (size_t)b * 3136 * 384 + c;
  float acc = 0.f;
  #pragma unroll
  for (int ky = 0; ky < 3; ky++) {
    const int iy = 2 * oy - 1 + ky;
    if (iy < 0 || iy >= 56) continue;
    #pragma unroll
    for (int kx = 0; kx < 3; kx++) {
      const int ix = 2 * ox - 1 + kx;
      if (ix < 0 || ix >= 56) continue;
      acc += wc[c * 9 + ky * 3 + kx] * xb[(size_t)(iy * 56 + ix) * 384];
    }
  }
  float s = acc, s2 = acc * acc;
  #pragma unroll
  for (int off = 32; off >= 1; off >>= 1) {
    s  += __shfl_xor(s,  off);
    s2 += __shfl_xor(s2, off);
  }
  __shared__ float ps[6], ps2[6];
  if ((c & 63) == 0) { ps[c >> 6] = s; ps2[c >> 6] = s2; }
  __syncthreads();
  float S = 0.f, S2 = 0.f;
  #pragma unroll
  for (int i = 0; i < 6; i++) { S += ps[i]; S2 += ps2[i]; }
  const float mu  = S * (1.f / 384.f);
  const float var = S2 * (1.f / 384.f) - mu * mu;
  const float inv = rsqrtf(var + 1e-5f);
  qout[((size_t)b * 784 + t) * 384 + c] = f2bf((acc - mu) * inv * g[c] + bb[c]);
}

// ---------- Kernel 2: 2x2 average pool -> bf16 ----------
__global__ __launch_bounds__(256) void k_pool(
    const float* __restrict__ x, ushort_t* __restrict__ kvout)
{
  const int idx = blockIdx.x * 256 + threadIdx.x;
  const int c = idx % 384;
  const int t = (idx / 384) % 784;
  const int b = idx / (384 * 784);
  const int ty = t / 28, tx = t % 28;
  const float* xb = x + (size_t)b * 3136 * 384 + c;
  const int r0 = (2 * ty) * 56 + 2 * tx;
  const float v = xb[(size_t)r0 * 384] + xb[(size_t)(r0 + 1) * 384]
                + xb[(size_t)(r0 + 56) * 384] + xb[(size_t)(r0 + 57) * 384];
  kvout[idx] = f2bf(v * 0.25f);
}

// ---------- Kernel 3: weights f32 -> bf16 ----------
__global__ __launch_bounds__(256) void k_wcvt(
    const float* __restrict__ a, const float* __restrict__ b,
    const float* __restrict__ c, const float* __restrict__ d,
    ushort_t* __restrict__ oa, ushort_t* __restrict__ ob,
    ushort_t* __restrict__ oc, ushort_t* __restrict__ od)
{
  const int i = blockIdx.x * 256 + threadIdx.x;
  if (i < 147456) {
    oa[i] = f2bf(a[i]); ob[i] = f2bf(b[i]);
    oc[i] = f2bf(c[i]); od[i] = f2bf(d[i]);
  }
}

// ---------- Kernel 4: dense MFMA GEMM, M=6272 N=384 K=384 ----------
template<int MODE>
__global__ __launch_bounds__(256) void k_gemm(
    const ushort_t* __restrict__ X, const ushort_t* __restrict__ W,
    const float* __restrict__ bias, void* __restrict__ Y)
{
  __shared__ ushort_t As[128][40];
  __shared__ ushort_t Bs[128][40];
  const int tid = threadIdx.x, w = tid >> 6, lane = tid & 63;
  const int quad = lane >> 4, r = lane & 15;
  const int m0 = blockIdx.y * 128, n0 = blockIdx.x * 128;
  const int wm = w >> 1, wn = w & 1;
  const int lr = tid >> 2, lc = (tid & 3) << 3;
  const ushort_t* xp = X + (size_t)(m0 + lr) * 384 + lc;
  const ushort_t* wp = W + (size_t)(n0 + lr) * 384 + lc;
  f32x4 acc[4][4] = {};
  for (int k0 = 0; k0 < 384; k0 += 32) {
    __syncthreads();
    *(uint4*)&As[lr][lc]      = *(const uint4*)(xp + k0);
    *(uint4*)&As[lr + 64][lc] = *(const uint4*)(xp + (size_t)64 * 384 + k0);
    *(uint4*)&Bs[lr][lc]      = *(const uint4*)(wp + k0);
    *(uint4*)&Bs[lr + 64][lc] = *(const uint4*)(wp + (size_t)64 * 384 + k0);
    __syncthreads();
    bf16x8 af[4], bf_[4];
    #pragma unroll
    for (int mt = 0; mt < 4; mt++) af[mt]  = *(const bf16x8*)&As[wm * 64 + mt * 16 + r][quad * 8];
    #pragma unroll
    for (int nt = 0; nt < 4; nt++) bf_[nt] = *(const bf16x8*)&Bs[wn * 64 + nt * 16 + r][quad * 8];
    #pragma unroll
    for (int mt = 0; mt < 4; mt++)
      #pragma unroll
      for (int nt = 0; nt < 4; nt++)
        acc[mt][nt] = __builtin_amdgcn_mfma_f32_16x16x32_bf16(af[mt], bf_[nt], acc[mt][nt], 0, 0, 0);
  }
  #pragma unroll
  for (int mt = 0; mt < 4; mt++) {
    #pragma unroll
    for (int nt = 0; nt < 4; nt++) {
      #pragma unroll
      for (int i = 0; i < 4; i++) {
        const int row = m0 + wm * 64 + mt * 16 + quad * 4 + i;
        const int col = n0 + wn * 64 + nt * 16 + r;
        const float v = acc[mt][nt][i];
        if constexpr (MODE == 2) {
          ((float*)Y)[(size_t)row * 384 + col] = v + bias[col];
        } else if constexpr (MODE == 0) {
          ((ushort_t*)Y)[(size_t)row * 384 + col] = f2bf(v);
        } else {
          const int bb = row / 784, tt = row % 784;
          ((ushort_t*)Y)[((size_t)bb * 384 + col) * 784 + tt] = f2bf(v);
        }
      }
    }
  }
}

// ---------- Kernel 5: residual premix ---------------------------------------
// R[b,l,o,t] = b_fuse[o] + sum_c w_fuse[o,6+c] * bilinear_upsample(res_attn[b,c])(l,t)
// One WG per (b,l); threads stride t. All loads coalesced f32 rows.
__global__ __launch_bounds__(256) void k_resmix(
    const float* __restrict__ ra, const float* __restrict__ w_fuse,
    const float* __restrict__ b_fuse, ushort_t* __restrict__ R)
{
  const int tid = threadIdx.x;
  const int b = blockIdx.x / 784, L = blockIdx.x % 784;
  __shared__ float w2[36], bfu[6];
  if (tid < 36) w2[tid] = w_fuse[(tid / 6) * 12 + 6 + (tid % 6)];
  if (tid < 6)  bfu[tid] = b_fuse[tid];
  __syncthreads();

  const int Yc = L / 28, Xc = L % 28;
  const float cy = fminf(fmaxf((float)Yc * 0.5f - 0.25f, 0.f), 13.f);
  const float cx = fminf(fmaxf((float)Xc * 0.5f - 0.25f, 0.f), 13.f);
  const int y0 = (int)cy, y1 = min(y0 + 1, 13);
  const int x0 = (int)cx, x1 = min(x0 + 1, 13);
  const float fy = cy - (float)y0, fx = cx - (float)x0;
  const float w00 = (1.f - fy) * (1.f - fx), w01 = (1.f - fy) * fx;
  const float w10 = fy * (1.f - fx),         w11 = fy * fx;
  const int p00 = (y0 * 14 + x0) * 784, p01 = (y0 * 14 + x1) * 784;
  const int p10 = (y1 * 14 + x0) * 784, p11 = (y1 * 14 + x1) * 784;

  const float* rab = ra + (size_t)b * 6 * 153664;
  ushort_t* Rrow = R + ((size_t)(b * 784 + L) * 6) * 784;

  for (int t = tid; t < 784; t += 256) {
    float U[6];
    #pragma unroll
    for (int c = 0; c < 6; c++) {
      const float* rc = rab + (size_t)c * 153664;
      U[c] = w00 * rc[p00 + t] + w01 * rc[p01 + t]
           + w10 * rc[p10 + t] + w11 * rc[p11 + t];
    }
    #pragma unroll
    for (int o = 0; o < 6; o++) {
      float v = bfu[o];
      #pragma unroll
      for (int c = 0; c < 6; c++) v += w2[o * 6 + c] * U[c];
      Rrow[(size_t)o * 784 + t] = f2bf(v);
    }
  }
}

// ---------- Kernel 6: fused flash attention, t-split 4-way -----------------
// Grid (392, 4). Scores mixed with precomputed R (head-mix of upsampled
// residual + bias). Writes unnormalized O-partials + (m,s); k_comb merges.
__global__ __launch_bounds__(256, 3) void k_fattn(
    const ushort_t* __restrict__ Qb, const ushort_t* __restrict__ Kb,
    const ushort_t* __restrict__ Vt, const ushort_t* __restrict__ R,
    const float* __restrict__ w_fuse,
    float* __restrict__ Op, float* __restrict__ Ms, float* __restrict__ Ss)
{
  __shared__ ushort_t Ssc[6][16][72];   // bf16 scores, 13824 B
  __shared__ ushort_t Pl[6][16][72];    // 13824 B
  __shared__ float m_st[6][16], s_st[6][16], a_st[6][16];
  __shared__ float w1[36];

  const int tid  = threadIdx.x;
  const int w    = tid >> 6, lane = tid & 63;
  const int quad = lane >> 4, r = lane & 15;
  const int b    = blockIdx.x & 7;
  const int m0   = (blockIdx.x >> 3) * 16;
  const int s    = blockIdx.y;
  const int tile0 = (s == 0) ? 0 : (3 * s + 1);  // 0-3 | 4-6 | 7-9 | 10-12
  const int tileN = (s == 0) ? 4 : 3;
  const float scale = 0.05103103630798288f; // 384^-0.5

  if (tid < 36) w1[tid] = w_fuse[(tid / 6) * 12 + (tid % 6)] * scale;
  if (tid < 96) { (&m_st[0][0])[tid] = -1e30f; (&s_st[0][0])[tid] = 0.f; }

  // persistent Q A-fragments (row l = m0 + r, all 6 heads x 2 k-steps)
  const ushort_t* qrow = Qb + ((size_t)(b * 784 + m0 + r)) * 384 + quad * 8;
  bf16x8 qf[6][2];
  #pragma unroll
  for (int h = 0; h < 6; h++) {
    qf[h][0] = ld_frag(qrow + h * 64);
    qf[h][1] = ld_frag(qrow + h * 64 + 32);
  }

  // phase-B thread mapping: l = tid>>4, 4 t's at tq*4
  const int bl_l = tid >> 4, tq = tid & 15;
  const ushort_t* Rrow = R + ((size_t)(b * 784 + m0 + bl_l) * 6) * 784;

  const size_t kbase  = (size_t)b * 784 * 384;
  const size_t vtbase = (size_t)b * 384 * 784;

  f32x4 oacc[6] = {};   // wave w holds (o=0..5, d-subtile = w)

  for (int ii = 0; ii < tileN; ii++) {
    const int t0 = (tile0 + ii) * 64;

    // ---- phase A: QK^T for t-subtile w (scale folded into w1) ----
    {
      const int tA = min(t0 + w * 16 + r, 783);
      const ushort_t* krow = Kb + kbase + (size_t)tA * 384 + quad * 8;
      #pragma unroll
      for (int h = 0; h < 6; h++) {
        f32x4 sc = {};
        sc = __builtin_amdgcn_mfma_f32_16x16x32_bf16(qf[h][0], ld_frag(krow + h * 64),      sc, 0, 0, 0);
        sc = __builtin_amdgcn_mfma_f32_16x16x32_bf16(qf[h][1], ld_frag(krow + h * 64 + 32), sc, 0, 0, 0);
        #pragma unroll
        for (int i = 0; i < 4; i++)
          Ssc[h][quad * 4 + i][w * 16 + r] = f2bf(sc[i]);
      }
    }
    __syncthreads();

    // ---- phase B: mix with R + online softmax ----
    {
      const int t4 = t0 + tq * 4;
      float F[6][4];
      #pragma unroll
      for (int o = 0; o < 6; o++) {
        const uint2 rv = *(const uint2*)(Rrow + (size_t)o * 784 + t4);
        F[o][0] = bflo(rv.x); F[o][1] = bfhi(rv.x);
        F[o][2] = bflo(rv.y); F[o][3] = bfhi(rv.y);
      }
      #pragma unroll
      for (int c = 0; c < 6; c++) {
        const uint2 sv = *(const uint2*)&Ssc[c][bl_l][tq * 4];
        const float s0 = bflo(sv.x), s1 = bfhi(sv.x);
        const float s2 = bflo(sv.y), s3 = bfhi(sv.y);
        #pragma unroll
        for (int o = 0; o < 6; o++) {
          const float wv = w1[o * 6 + c];
          F[o][0] += wv * s0; F[o][1] += wv * s1;
          F[o][2] += wv * s2; F[o][3] += wv * s3;
        }
      }
      #pragma unroll
      for (int j = 0; j < 4; j++) {
        if (t4 + j >= 784) {
          #pragma unroll
          for (int o = 0; o < 6; o++) F[o][j] = -1e30f;
        }
      }
      #pragma unroll
      for (int o = 0; o < 6; o++) {
        float mx = fmaxf(fmaxf(F[o][0], F[o][1]), fmaxf(F[o][2], F[o][3]));
        #pragma unroll
        for (int off = 8; off >= 1; off >>= 1) mx = fmaxf(mx, __shfl_xor(mx, off));
        const float m_old = m_st[o][bl_l];
        const float nm = fmaxf(m_old, mx);
        const float al = __expf(m_old - nm);
        float p0 = __expf(F[o][0] - nm), p1 = __expf(F[o][1] - nm);
        float p2 = __expf(F[o][2] - nm), p3 = __expf(F[o][3] - nm);
        float sm = p0 + p1 + p2 + p3;
        #pragma unroll
        for (int off = 8; off >= 1; off >>= 1) sm += __shfl_xor(sm, off);
        const uint lo = (uint)f2bf(p0) | ((uint)f2bf(p1) << 16);
        const uint hi = (uint)f2bf(p2) | ((uint)f2bf(p3) << 16);
        *(uint2*)&Pl[o][bl_l][tq * 4] = uint2{lo, hi};
        if (tq == 0) {
          m_st[o][bl_l] = nm;
          s_st[o][bl_l] = s_st[o][bl_l] * al + sm;
          a_st[o][bl_l] = al;
        }
      }
    }
    __syncthreads();

    // ---- phase C: O = O*alpha + P.V (d-subtile w) ----
    #pragma unroll
    for (int o = 0; o < 6; o++) {
      const f32x4 al4 = *(const f32x4*)&a_st[o][quad * 4];
      oacc[o] *= al4;
      const bf16x8 pa0 = *(const bf16x8*)&Pl[o][r][quad * 8];
      const bf16x8 pa1 = *(const bf16x8*)&Pl[o][r][quad * 8 + 32];
      const ushort_t* vrow = Vt + vtbase + (size_t)(o * 64 + w * 16 + r) * 784 + t0 + quad * 8;
      oacc[o] = __builtin_amdgcn_mfma_f32_16x16x32_bf16(pa0, ld_frag(vrow),      oacc[o], 0, 0, 0);
      oacc[o] = __builtin_amdgcn_mfma_f32_16x16x32_bf16(pa1, ld_frag(vrow + 32), oacc[o], 0, 0, 0);
    }
    __syncthreads();
  }

  // ---- epilogue: write unnormalized partial O + (m,s) state ----
  const size_t prow = (size_t)s * 6272 + (size_t)b * 784 + m0;
  #pragma unroll
  for (int o = 0; o < 6; o++) {
    #pragma unroll
    for (int i = 0; i < 4; i++) {
      Op[(prow + quad * 4 + i) * 384 + o * 64 + w * 16 + r] = oacc[o][i];
    }
  }
  if (tid < 96) {
    const int o = tid >> 4, l = tid & 15;
    Ms[(prow + l) * 6 + o] = m_st[o][l];
    Ss[(prow + l) * 6 + o] = s_st[o][l];
  }
}

// ---------- Kernel 7: combine 4 t-split partials -> normalized bf16 O -------
__global__ __launch_bounds__(256) void k_comb(
    const float* __restrict__ Op, const float* __restrict__ Ms,
    const float* __restrict__ Ss, ushort_t* __restrict__ O)
{
  const int idx = blockIdx.x * 256 + threadIdx.x;   // 2,408,448 total
  const int row = idx / 384, col = idx % 384, o = col >> 6;
  float m = -1e30f;
  #pragma unroll
  for (int s = 0; s < 4; s++) m = fmaxf(m, Ms[((size_t)s * 6272 + row) * 6 + o]);
  float S = 0.f, acc = 0.f;
  #pragma unroll
  for (int s = 0; s < 4; s++) {
    const size_t pr = (size_t)s * 6272 + row;
    const float e = __expf(Ms[pr * 6 + o] - m);
    S   += Ss[pr * 6 + o] * e;
    acc += Op[pr * 384 + col] * e;
  }
  O[(size_t)row * 384 + col] = f2bf(acc / S);
}

// ---------- host launcher ----------
extern "C" void kernel_launch(void* const* d_in, const int* in_sizes, int n_in,
                              void* d_out, int out_size, void* d_ws, size_t ws_size,
                              hipStream_t stream)
{
  const float* x        = (const float*)d_in[0];
  const float* res_attn = (const float*)d_in[1];
  const float* conv_w   = (const float*)d_in[2];
  const float* ln_g     = (const float*)d_in[3];
  const float* ln_b     = (const float*)d_in[4];
  const float* wq       = (const float*)d_in[5];
  const float* wk       = (const float*)d_in[6];
  const float* wv       = (const float*)d_in[7];
  const float* w_proj   = (const float*)d_in[8];
  const float* b_proj   = (const float*)d_in[9];
  const float* w_fuse   = (const float*)d_in[10];
  const float* b_fuse   = (const float*)d_in[11];
  float* out = (float*)d_out;

  const size_t NE = (size_t)8 * 784 * 384;       // 2,408,448
  const size_t NW = 147456;
  const size_t NR = (size_t)8 * 784 * 6 * 784;   // 29,503,488
  ushort_t* q_ln_b = (ushort_t*)d_ws;
  ushort_t* kv_b   = q_ln_b + NE;
  ushort_t* Qb     = kv_b + NE;
  ushort_t* Kb     = Qb + NE;
  ushort_t* Vt     = Kb + NE;        // (b, 384, 784) + 64-elem pad
  ushort_t* Opre   = Vt + NE + 64;
  ushort_t* wqb    = Opre + NE;
  ushort_t* wkb    = wqb + NW;
  ushort_t* wvb    = wkb + NW;
  ushort_t* wpb    = wvb + NW;
  ushort_t* R      = wpb + NW;            // (b,784,6,784) bf16 + pad
  float*    Op     = (float*)(R + NR + 512);  // [4][6272][384] f32
  float*    Ms     = Op + 4 * NE;             // [4][6272][6]
  float*    Ss     = Ms + 4 * 6272 * 6;

  k_convln<<<dim3(8 * 784), dim3(384), 0, stream>>>(x, conv_w, ln_g, ln_b, q_ln_b);
  k_pool  <<<dim3(9408),    dim3(256), 0, stream>>>(x, kv_b);
  k_wcvt  <<<dim3(576),     dim3(256), 0, stream>>>(wq, wk, wv, w_proj, wqb, wkb, wvb, wpb);
  k_resmix<<<dim3(8 * 784), dim3(256), 0, stream>>>(res_attn, w_fuse, b_fuse, R);

  k_gemm<0><<<dim3(3, 49), dim3(256), 0, stream>>>(q_ln_b, wqb, nullptr, Qb);
  k_gemm<0><<<dim3(3, 49), dim3(256), 0, stream>>>(kv_b,   wkb, nullptr, Kb);
  k_gemm<1><<<dim3(3, 49), dim3(256), 0, stream>>>(kv_b,   wvb, nullptr, Vt);

  k_fattn<<<dim3(392, 4), dim3(256), 0, stream>>>(Qb, Kb, Vt, R, w_fuse, Op, Ms, Ss);
  k_comb <<<dim3(9408),   dim3(256), 0, stream>>>(Op, Ms, Ss, Opre);

  k_gemm<2><<<dim3(3, 49), dim3(256), 0, stream>>>(Opre, wpb, b_proj, out);
}

// Round 7
// 354.158 us; speedup vs baseline: 1.1337x; 1.0543x over previous
//
#include <hip/hip_runtime.h>

typedef unsigned int uint;
typedef unsigned short ushort_t;
typedef short bf16x8 __attribute__((ext_vector_type(8)));
typedef float f32x4 __attribute__((ext_vector_type(4)));

// ---------- bf16 helpers ----------
__device__ __forceinline__ ushort_t f2bf(float f) {
  uint u = __builtin_bit_cast(uint, f);
  u += 0x7fffu + ((u >> 16) & 1u);
  return (ushort_t)(u >> 16);
}
__device__ __forceinline__ float bf2f(ushort_t s) {
  return __builtin_bit_cast(float, (uint)s << 16);
}
__device__ __forceinline__ float bflo(uint u) { return __builtin_bit_cast(float, u << 16); }
__device__ __forceinline__ float bfhi(uint u) { return __builtin_bit_cast(float, u & 0xffff0000u); }
__device__ __forceinline__ bf16x8 ld_frag(const ushort_t* p) {
  return __builtin_bit_cast(bf16x8, *(const uint4*)p);
}

// ---------- Kernel 1: depthwise conv3x3 s2 p1 + LayerNorm + 2x2 avgpool ----
// One block per (b,t) on the 28x28 grid; thread = channel. Pool taps are a
// subset of the conv taps, so both outputs come from the same 9 loads.
__global__ __launch_bounds__(384) void k_prep(
    const float* __restrict__ x, const float* __restrict__ wc,
    const float* __restrict__ g, const float* __restrict__ bb,
    ushort_t* __restrict__ qout, ushort_t* __restrict__ kvout)
{
  const int b  = blockIdx.x / 784;
  const int t  = blockIdx.x % 784;
  const int oy = t / 28, ox = t % 28;
  const int c  = threadIdx.x;
  const float* xb = x + (size_t)b * 3136 * 384 + c;
  float tap[9];
  #pragma unroll
  for (int ky = 0; ky < 3; ky++) {
    const int iy = 2 * oy - 1 + ky;
    #pragma unroll
    for (int kx = 0; kx < 3; kx++) {
      const int ix = 2 * ox - 1 + kx;
      tap[ky * 3 + kx] = (iy >= 0 && iy < 56 && ix >= 0 && ix < 56)
                         ? xb[(size_t)(iy * 56 + ix) * 384] : 0.f;
    }
  }
  float acc = 0.f;
  #pragma unroll
  for (int k = 0; k < 9; k++) acc += wc[c * 9 + k] * tap[k];
  const float pool = (tap[4] + tap[5] + tap[7] + tap[8]) * 0.25f;

  float s = acc, s2 = acc * acc;
  #pragma unroll
  for (int off = 32; off >= 1; off >>= 1) {
    s  += __shfl_xor(s,  off);
    s2 += __shfl_xor(s2, off);
  }
  __shared__ float ps[6], ps2[6];
  if ((c & 63) == 0) { ps[c >> 6] = s; ps2[c >> 6] = s2; }
  __syncthreads();
  float S = 0.f, S2 = 0.f;
  #pragma unroll
  for (int i = 0; i < 6; i++) { S += ps[i]; S2 += ps2[i]; }
  const float mu  = S * (1.f / 384.f);
  const float var = S2 * (1.f / 384.f) - mu * mu;
  const float inv = rsqrtf(var + 1e-5f);
  const size_t o = ((size_t)b * 784 + t) * 384 + c;
  qout[o]  = f2bf((acc - mu) * inv * g[c] + bb[c]);
  kvout[o] = f2bf(pool);
}

// ---------- Kernel 2: weights f32 -> bf16 ----------
__global__ __launch_bounds__(256) void k_wcvt(
    const float* __restrict__ a, const float* __restrict__ b,
    const float* __restrict__ c, const float* __restrict__ d,
    ushort_t* __restrict__ oa, ushort_t* __restrict__ ob,
    ushort_t* __restrict__ oc, ushort_t* __restrict__ od)
{
  const int i = blockIdx.x * 256 + threadIdx.x;
  if (i < 147456) {
    oa[i] = f2bf(a[i]); ob[i] = f2bf(b[i]);
    oc[i] = f2bf(c[i]); od[i] = f2bf(d[i]);
  }
}

// ---------- Kernel 3: coarse residual premix --------------------------------
// RC[b,o,lc,t] = sum_c w_fuse[o,6+c] * res_attn[b,c,lc,t]  (bf16, 14.8 MB).
// Bilinear l-interpolation happens inside k_fattn (RC is L2-resident).
__global__ __launch_bounds__(256) void k_rcmix(
    const float* __restrict__ ra, const float* __restrict__ w_fuse,
    ushort_t* __restrict__ RC)
{
  const int tid = threadIdx.x;
  const int b = blockIdx.x / 196, lc = blockIdx.x % 196;
  __shared__ float w2[36];
  if (tid < 36) w2[tid] = w_fuse[(tid / 6) * 12 + 6 + (tid % 6)];
  __syncthreads();
  const float* rab = ra + ((size_t)b * 6 * 196 + lc) * 784;
  ushort_t* RCb = RC + ((size_t)b * 6 * 196 + lc) * 784;
  for (int t = tid; t < 784; t += 256) {
    float U[6];
    #pragma unroll
    for (int c = 0; c < 6; c++) U[c] = rab[(size_t)c * 153664 + t];
    #pragma unroll
    for (int o = 0; o < 6; o++) {
      float v = 0.f;
      #pragma unroll
      for (int c = 0; c < 6; c++) v += w2[o * 6 + c] * U[c];
      RCb[(size_t)o * 153664 + t] = f2bf(v);
    }
  }
}

// ---------- Kernel 4: dense MFMA GEMM, Y[m,n]=X[m,:].W[n,:] -----------------
// MODE 0: bf16 row-major out; MODE 2: f32 + bias out.
template<int MODE>
__global__ __launch_bounds__(256) void k_gemm(
    const ushort_t* __restrict__ X, const ushort_t* __restrict__ W,
    const float* __restrict__ bias, void* __restrict__ Y)
{
  __shared__ ushort_t As[128][40];
  __shared__ ushort_t Bs[128][40];
  const int tid = threadIdx.x, w = tid >> 6, lane = tid & 63;
  const int quad = lane >> 4, r = lane & 15;
  const int m0 = blockIdx.y * 128, n0 = blockIdx.x * 128;
  const int wm = w >> 1, wn = w & 1;
  const int lr = tid >> 2, lc = (tid & 3) << 3;
  const ushort_t* xp = X + (size_t)(m0 + lr) * 384 + lc;
  const ushort_t* wp = W + (size_t)(n0 + lr) * 384 + lc;
  f32x4 acc[4][4] = {};
  for (int k0 = 0; k0 < 384; k0 += 32) {
    __syncthreads();
    *(uint4*)&As[lr][lc]      = *(const uint4*)(xp + k0);
    *(uint4*)&As[lr + 64][lc] = *(const uint4*)(xp + (size_t)64 * 384 + k0);
    *(uint4*)&Bs[lr][lc]      = *(const uint4*)(wp + k0);
    *(uint4*)&Bs[lr + 64][lc] = *(const uint4*)(wp + (size_t)64 * 384 + k0);
    __syncthreads();
    bf16x8 af[4], bf_[4];
    #pragma unroll
    for (int mt = 0; mt < 4; mt++) af[mt]  = *(const bf16x8*)&As[wm * 64 + mt * 16 + r][quad * 8];
    #pragma unroll
    for (int nt = 0; nt < 4; nt++) bf_[nt] = *(const bf16x8*)&Bs[wn * 64 + nt * 16 + r][quad * 8];
    #pragma unroll
    for (int mt = 0; mt < 4; mt++)
      #pragma unroll
      for (int nt = 0; nt < 4; nt++)
        acc[mt][nt] = __builtin_amdgcn_mfma_f32_16x16x32_bf16(af[mt], bf_[nt], acc[mt][nt], 0, 0, 0);
  }
  #pragma unroll
  for (int mt = 0; mt < 4; mt++) {
    #pragma unroll
    for (int nt = 0; nt < 4; nt++) {
      #pragma unroll
      for (int i = 0; i < 4; i++) {
        const int row = m0 + wm * 64 + mt * 16 + quad * 4 + i;
        const int col = n0 + wn * 64 + nt * 16 + r;
        const float v = acc[mt][nt][i];
        if constexpr (MODE == 2) ((float*)Y)[(size_t)row * 384 + col] = v + bias[col];
        else                     ((ushort_t*)Y)[(size_t)row * 384 + col] = f2bf(v);
      }
    }
  }
}

// ---------- Kernel 5: V GEMM with swapped roles: D = W.X^T ------------------
// M=384 (d-rows), N=6272 (tokens). C-frag cols are tokens -> Vt stores are
// contiguous 32B segments (fixes the 1568B-stride scalar scatter of old MODE 1).
__global__ __launch_bounds__(256) void k_gemmT(
    const ushort_t* __restrict__ W, const ushort_t* __restrict__ X,
    ushort_t* __restrict__ Vt)
{
  __shared__ ushort_t As[128][40];
  __shared__ ushort_t Bs[128][40];
  const int tid = threadIdx.x, w = tid >> 6, lane = tid & 63;
  const int quad = lane >> 4, r = lane & 15;
  const int m0 = blockIdx.y * 128, n0 = blockIdx.x * 128;
  const int wm = w >> 1, wn = w & 1;
  const int lr = tid >> 2, lc = (tid & 3) << 3;
  const ushort_t* ap = W + (size_t)(m0 + lr) * 384 + lc;
  const ushort_t* bp = X + (size_t)(n0 + lr) * 384 + lc;
  f32x4 acc[4][4] = {};
  for (int k0 = 0; k0 < 384; k0 += 32) {
    __syncthreads();
    *(uint4*)&As[lr][lc]      = *(const uint4*)(ap + k0);
    *(uint4*)&As[lr + 64][lc] = *(const uint4*)(ap + (size_t)64 * 384 + k0);
    *(uint4*)&Bs[lr][lc]      = *(const uint4*)(bp + k0);
    *(uint4*)&Bs[lr + 64][lc] = *(const uint4*)(bp + (size_t)64 * 384 + k0);
    __syncthreads();
    bf16x8 af[4], bf_[4];
    #pragma unroll
    for (int mt = 0; mt < 4; mt++) af[mt]  = *(const bf16x8*)&As[wm * 64 + mt * 16 + r][quad * 8];
    #pragma unroll
    for (int nt = 0; nt < 4; nt++) bf_[nt] = *(const bf16x8*)&Bs[wn * 64 + nt * 16 + r][quad * 8];
    #pragma unroll
    for (int mt = 0; mt < 4; mt++)
      #pragma unroll
      for (int nt = 0; nt < 4; nt++)
        acc[mt][nt] = __builtin_amdgcn_mfma_f32_16x16x32_bf16(af[mt], bf_[nt], acc[mt][nt], 0, 0, 0);
  }
  #pragma unroll
  for (int mt = 0; mt < 4; mt++) {
    #pragma unroll
    for (int nt = 0; nt < 4; nt++) {
      #pragma unroll
      for (int i = 0; i < 4; i++) {
        const int d   = m0 + wm * 64 + mt * 16 + quad * 4 + i;
        const int tok = n0 + wn * 64 + nt * 16 + r;
        const int b = tok / 784, tt = tok % 784;
        Vt[((size_t)b * 384 + d) * 784 + tt] = f2bf(acc[mt][nt][i]);
      }
    }
  }
}

// ---------- Kernel 6: fused flash attention, t-split 4-way ------------------
// Grid (392, 4). Phase B does the bilinear l-interp of RC inline (RC is
// L2-resident per batch). Epilogue stages O-partials through LDS for full-line
// float4 writes; (m,s) packed float2.
__global__ __launch_bounds__(256, 3) void k_fattn(
    const ushort_t* __restrict__ Qb, const ushort_t* __restrict__ Kb,
    const ushort_t* __restrict__ Vt, const ushort_t* __restrict__ RC,
    const float* __restrict__ w_fuse, const float* __restrict__ b_fuse,
    float* __restrict__ Op, float2* __restrict__ MS)
{
  __shared__ char smem[27648];          // Ssc(13824) + Pl(13824); epilogue: stage(25088)
  ushort_t* Ssc_ = (ushort_t*)smem;     // [6][16][72]
  ushort_t* Pl_  = (ushort_t*)(smem + 13824);
  float*    stage = (float*)smem;       // [16][392]
  #define SSC(h, l, t) Ssc_[(((h) * 16 + (l)) * 72) + (t)]
  #define PL(h, l, t)  Pl_[(((h) * 16 + (l)) * 72) + (t)]
  __shared__ float m_st[6][16], s_st[6][16], a_st[6][16];
  __shared__ float w1[36], bfu[6];

  const int tid  = threadIdx.x;
  const int w    = tid >> 6, lane = tid & 63;
  const int quad = lane >> 4, r = lane & 15;
  const int b    = blockIdx.x & 7;
  const int m0   = (blockIdx.x >> 3) * 16;
  const int s    = blockIdx.y;
  const int tile0 = (s == 0) ? 0 : (3 * s + 1);  // 0-3 | 4-6 | 7-9 | 10-12
  const int tileN = (s == 0) ? 4 : 3;
  const float scale = 0.05103103630798288f; // 384^-0.5

  if (tid < 36) w1[tid] = w_fuse[(tid / 6) * 12 + (tid % 6)] * scale;
  if (tid < 6)  bfu[tid] = b_fuse[tid];
  if (tid < 96) { (&m_st[0][0])[tid] = -1e30f; (&s_st[0][0])[tid] = 0.f; }

  // persistent Q A-fragments (row l = m0 + r, all 6 heads x 2 k-steps)
  const ushort_t* qrow = Qb + ((size_t)(b * 784 + m0 + r)) * 384 + quad * 8;
  bf16x8 qf[6][2];
  #pragma unroll
  for (int h = 0; h < 6; h++) {
    qf[h][0] = ld_frag(qrow + h * 64);
    qf[h][1] = ld_frag(qrow + h * 64 + 32);
  }

  // phase-B thread mapping: l = tid>>4, 4 t's at tq*4; bilinear corner setup
  const int bl_l = tid >> 4, tq = tid & 15;
  const int L = m0 + bl_l;
  const int Yc = L / 28, Xc = L % 28;
  const float cy = fminf(fmaxf((float)Yc * 0.5f - 0.25f, 0.f), 13.f);
  const float cx = fminf(fmaxf((float)Xc * 0.5f - 0.25f, 0.f), 13.f);
  const int y0 = (int)cy, y1 = min(y0 + 1, 13);
  const int x0 = (int)cx, x1 = min(x0 + 1, 13);
  const float fy = cy - (float)y0, fx = cx - (float)x0;
  const float w00 = (1.f - fy) * (1.f - fx), w01 = (1.f - fy) * fx;
  const float w10 = fy * (1.f - fx),         w11 = fy * fx;
  const int q00 = (y0 * 14 + x0) * 784, q01 = (y0 * 14 + x1) * 784;
  const int q10 = (y1 * 14 + x0) * 784, q11 = (y1 * 14 + x1) * 784;
  const ushort_t* RCb = RC + (size_t)b * 6 * 153664;

  const size_t kbase  = (size_t)b * 784 * 384;
  const size_t vtbase = (size_t)b * 384 * 784;

  f32x4 oacc[6] = {};   // (o = head, d-subtile = wave w)

  for (int ii = 0; ii < tileN; ii++) {
    const int t0 = (tile0 + ii) * 64;

    // ---- phase A: QK^T for t-subtile w (scale folded into w1) ----
    {
      const int tA = min(t0 + w * 16 + r, 783);
      const ushort_t* krow = Kb + kbase + (size_t)tA * 384 + quad * 8;
      #pragma unroll
      for (int h = 0; h < 6; h++) {
        f32x4 sc = {};
        sc = __builtin_amdgcn_mfma_f32_16x16x32_bf16(qf[h][0], ld_frag(krow + h * 64),      sc, 0, 0, 0);
        sc = __builtin_amdgcn_mfma_f32_16x16x32_bf16(qf[h][1], ld_frag(krow + h * 64 + 32), sc, 0, 0, 0);
        #pragma unroll
        for (int i = 0; i < 4; i++)
          SSC(h, quad * 4 + i, w * 16 + r) = f2bf(sc[i]);
      }
    }
    __syncthreads();

    // ---- phase B: bilinear RC + head-mix + online softmax ----
    {
      const int t4 = t0 + tq * 4;
      float F[6][4];
      #pragma unroll
      for (int o = 0; o < 6; o++) {
        const ushort_t* rco = RCb + (size_t)o * 153664 + t4;
        const uint2 u00 = *(const uint2*)(rco + q00);
        const uint2 u01 = *(const uint2*)(rco + q01);
        const uint2 u10 = *(const uint2*)(rco + q10);
        const uint2 u11 = *(const uint2*)(rco + q11);
        F[o][0] = bfu[o] + w00 * bflo(u00.x) + w01 * bflo(u01.x) + w10 * bflo(u10.x) + w11 * bflo(u11.x);
        F[o][1] = bfu[o] + w00 * bfhi(u00.x) + w01 * bfhi(u01.x) + w10 * bfhi(u10.x) + w11 * bfhi(u11.x);
        F[o][2] = bfu[o] + w00 * bflo(u00.y) + w01 * bflo(u01.y) + w10 * bflo(u10.y) + w11 * bflo(u11.y);
        F[o][3] = bfu[o] + w00 * bfhi(u00.y) + w01 * bfhi(u01.y) + w10 * bfhi(u10.y) + w11 * bfhi(u11.y);
      }
      #pragma unroll
      for (int c = 0; c < 6; c++) {
        const uint2 sv = *(const uint2*)&SSC(c, bl_l, tq * 4);
        const float s0 = bflo(sv.x), s1 = bfhi(sv.x);
        const float s2 = bflo(sv.y), s3 = bfhi(sv.y);
        #pragma unroll
        for (int o = 0; o < 6; o++) {
          const float wv = w1[o * 6 + c];
          F[o][0] += wv * s0; F[o][1] += wv * s1;
          F[o][2] += wv * s2; F[o][3] += wv * s3;
        }
      }
      #pragma unroll
      for (int j = 0; j < 4; j++) {
        if (t4 + j >= 784) {
          #pragma unroll
          for (int o = 0; o < 6; o++) F[o][j] = -1e30f;
        }
      }
      #pragma unroll
      for (int o = 0; o < 6; o++) {
        float mx = fmaxf(fmaxf(F[o][0], F[o][1]), fmaxf(F[o][2], F[o][3]));
        #pragma unroll
        for (int off = 8; off >= 1; off >>= 1) mx = fmaxf(mx, __shfl_xor(mx, off));
        const float m_old = m_st[o][bl_l];
        const float nm = fmaxf(m_old, mx);
        const float al = __expf(m_old - nm);
        float p0 = __expf(F[o][0] - nm), p1 = __expf(F[o][1] - nm);
        float p2 = __expf(F[o][2] - nm), p3 = __expf(F[o][3] - nm);
        float sm = p0 + p1 + p2 + p3;
        #pragma unroll
        for (int off = 8; off >= 1; off >>= 1) sm += __shfl_xor(sm, off);
        const uint lo = (uint)f2bf(p0) | ((uint)f2bf(p1) << 16);
        const uint hi = (uint)f2bf(p2) | ((uint)f2bf(p3) << 16);
        *(uint2*)&PL(o, bl_l, tq * 4) = uint2{lo, hi};
        if (tq == 0) {
          m_st[o][bl_l] = nm;
          s_st[o][bl_l] = s_st[o][bl_l] * al + sm;
          a_st[o][bl_l] = al;
        }
      }
    }
    __syncthreads();

    // ---- phase C: O = O*alpha + P.V (d-subtile w) ----
    #pragma unroll
    for (int o = 0; o < 6; o++) {
      const f32x4 al4 = *(const f32x4*)&a_st[o][quad * 4];
      oacc[o] *= al4;
      const bf16x8 pa0 = *(const bf16x8*)&PL(o, r, quad * 8);
      const bf16x8 pa1 = *(const bf16x8*)&PL(o, r, quad * 8 + 32);
      const ushort_t* vrow = Vt + vtbase + (size_t)(o * 64 + w * 16 + r) * 784 + t0 + quad * 8;
      oacc[o] = __builtin_amdgcn_mfma_f32_16x16x32_bf16(pa0, ld_frag(vrow),      oacc[o], 0, 0, 0);
      oacc[o] = __builtin_amdgcn_mfma_f32_16x16x32_bf16(pa1, ld_frag(vrow + 32), oacc[o], 0, 0, 0);
    }
    __syncthreads();
  }

  // ---- epilogue: LDS transpose -> coalesced float4 stores ----
  #pragma unroll
  for (int o = 0; o < 6; o++)
    #pragma unroll
    for (int i = 0; i < 4; i++)
      stage[(quad * 4 + i) * 392 + o * 64 + w * 16 + r] = oacc[o][i];
  __syncthreads();
  const size_t prow = (size_t)s * 6272 + (size_t)b * 784 + m0;
  #pragma unroll
  for (int j = 0; j < 6; j++) {
    const int idx = tid + j * 256;
    const int row = idx / 96, c4 = idx % 96;
    *(float4*)&Op[(prow + row) * 384 + c4 * 4] = *(const float4*)&stage[row * 392 + c4 * 4];
  }
  if (tid < 96) {
    const int l = tid / 6, o = tid % 6;
    MS[(prow + l) * 6 + o] = float2{m_st[o][l], s_st[o][l]};
  }
  #undef SSC
  #undef PL
}

// ---------- Kernel 7: combine 4 t-split partials -> normalized bf16 O -------
__global__ __launch_bounds__(256) void k_comb(
    const float* __restrict__ Op, const float2* __restrict__ MS,
    ushort_t* __restrict__ O)
{
  const int idx = blockIdx.x * 256 + threadIdx.x;   // 2,408,448 total
  const int row = idx / 384, col = idx % 384, o = col >> 6;
  float2 ms[4];
  #pragma unroll
  for (int s = 0; s < 4; s++) ms[s] = MS[((size_t)s * 6272 + row) * 6 + o];
  float m = fmaxf(fmaxf(ms[0].x, ms[1].x), fmaxf(ms[2].x, ms[3].x));
  float S = 0.f, acc = 0.f;
  #pragma unroll
  for (int s = 0; s < 4; s++) {
    const float e = __expf(ms[s].x - m);
    S   += ms[s].y * e;
    acc += Op[((size_t)s * 6272 + row) * 384 + col] * e;
  }
  O[(size_t)row * 384 + col] = f2bf(acc / S);
}

// ---------- host launcher ----------
extern "C" void kernel_launch(void* const* d_in, const int* in_sizes, int n_in,
                              void* d_out, int out_size, void* d_ws, size_t ws_size,
                              hipStream_t stream)
{
  const float* x        = (const float*)d_in[0];
  const float* res_attn = (const float*)d_in[1];
  const float* conv_w   = (const float*)d_in[2];
  const float* ln_g     = (const float*)d_in[3];
  const float* ln_b     = (const float*)d_in[4];
  const float* wq       = (const float*)d_in[5];
  const float* wk       = (const float*)d_in[6];
  const float* wv       = (const float*)d_in[7];
  const float* w_proj   = (const float*)d_in[8];
  const float* b_proj   = (const float*)d_in[9];
  const float* w_fuse   = (const float*)d_in[10];
  const float* b_fuse   = (const float*)d_in[11];
  float* out = (float*)d_out;

  const size_t NE  = (size_t)8 * 784 * 384;       // 2,408,448
  const size_t NW  = 147456;
  const size_t NRC = (size_t)8 * 6 * 196 * 784;   // 7,375,872
  ushort_t* q_ln_b = (ushort_t*)d_ws;
  ushort_t* kv_b   = q_ln_b + NE;
  ushort_t* Qb     = kv_b + NE;
  ushort_t* Kb     = Qb + NE;
  ushort_t* Vt     = Kb + NE;            // (b, 384, 784) + pad
  ushort_t* Opre   = Vt + NE + 64;
  ushort_t* wqb    = Opre + NE;
  ushort_t* wkb    = wqb + NW;
  ushort_t* wvb    = wkb + NW;
  ushort_t* wpb    = wvb + NW;
  ushort_t* RC     = wpb + NW;           // (b,6,196,784) bf16 + pad
  float*    Op     = (float*)(RC + NRC + 64);  // [4][6272][384] f32
  float2*   MS     = (float2*)(Op + 4 * NE);   // [4][6272][6]

  k_prep <<<dim3(8 * 784), dim3(384), 0, stream>>>(x, conv_w, ln_g, ln_b, q_ln_b, kv_b);
  k_wcvt <<<dim3(576),     dim3(256), 0, stream>>>(wq, wk, wv, w_proj, wqb, wkb, wvb, wpb);
  k_rcmix<<<dim3(8 * 196), dim3(256), 0, stream>>>(res_attn, w_fuse, RC);

  k_gemm<0><<<dim3(3, 49), dim3(256), 0, stream>>>(q_ln_b, wqb, nullptr, Qb);
  k_gemm<0><<<dim3(3, 49), dim3(256), 0, stream>>>(kv_b,   wkb, nullptr, Kb);
  k_gemmT  <<<dim3(49, 3), dim3(256), 0, stream>>>(wvb, kv_b, Vt);

  k_fattn<<<dim3(392, 4), dim3(256), 0, stream>>>(Qb, Kb, Vt, RC, w_fuse, b_fuse, Op, MS);
  k_comb <<<dim3(9408),   dim3(256), 0, stream>>>(Op, MS, Opre);

  k_gemm<2><<<dim3(3, 49), dim3(256), 0, stream>>>(Opre, wpb, b_proj, out);
}

// Round 8
// 338.782 us; speedup vs baseline: 1.1851x; 1.0454x over previous
//
#include <hip/hip_runtime.h>

typedef unsigned int uint;
typedef unsigned short ushort_t;
typedef short bf16x8 __attribute__((ext_vector_type(8)));
typedef float f32x4 __attribute__((ext_vector_type(4)));

// ---------- bf16 helpers ----------
__device__ __forceinline__ ushort_t f2bf(float f) {
  uint u = __builtin_bit_cast(uint, f);
  u += 0x7fffu + ((u >> 16) & 1u);
  return (ushort_t)(u >> 16);
}
__device__ __forceinline__ float bf2f(ushort_t s) {
  return __builtin_bit_cast(float, (uint)s << 16);
}
__device__ __forceinline__ float bflo(uint u) { return __builtin_bit_cast(float, u << 16); }
__device__ __forceinline__ float bfhi(uint u) { return __builtin_bit_cast(float, u & 0xffff0000u); }
__device__ __forceinline__ bf16x8 ld_frag(const ushort_t* p) {
  return __builtin_bit_cast(bf16x8, *(const uint4*)p);
}

// ---------- Kernel 1: depthwise conv3x3 s2 p1 + LayerNorm + 2x2 avgpool ----
// XCD-affine: b = blockIdx&7 so each XCD's L2 holds one batch slice of x.
__global__ __launch_bounds__(384) void k_prep(
    const float* __restrict__ x, const float* __restrict__ wc,
    const float* __restrict__ g, const float* __restrict__ bb,
    ushort_t* __restrict__ qout, ushort_t* __restrict__ kvout)
{
  const int b  = blockIdx.x & 7;
  const int t  = blockIdx.x >> 3;
  const int oy = t / 28, ox = t % 28;
  const int c  = threadIdx.x;
  const float* xb = x + (size_t)b * 3136 * 384 + c;
  float tap[9];
  #pragma unroll
  for (int ky = 0; ky < 3; ky++) {
    const int iy = 2 * oy - 1 + ky;
    #pragma unroll
    for (int kx = 0; kx < 3; kx++) {
      const int ix = 2 * ox - 1 + kx;
      tap[ky * 3 + kx] = (iy >= 0 && iy < 56 && ix >= 0 && ix < 56)
                         ? xb[(size_t)(iy * 56 + ix) * 384] : 0.f;
    }
  }
  float acc = 0.f;
  #pragma unroll
  for (int k = 0; k < 9; k++) acc += wc[c * 9 + k] * tap[k];
  const float pool = (tap[4] + tap[5] + tap[7] + tap[8]) * 0.25f;

  float s = acc, s2 = acc * acc;
  #pragma unroll
  for (int off = 32; off >= 1; off >>= 1) {
    s  += __shfl_xor(s,  off);
    s2 += __shfl_xor(s2, off);
  }
  __shared__ float ps[6], ps2[6];
  if ((c & 63) == 0) { ps[c >> 6] = s; ps2[c >> 6] = s2; }
  __syncthreads();
  float S = 0.f, S2 = 0.f;
  #pragma unroll
  for (int i = 0; i < 6; i++) { S += ps[i]; S2 += ps2[i]; }
  const float mu  = S * (1.f / 384.f);
  const float var = S2 * (1.f / 384.f) - mu * mu;
  const float inv = rsqrtf(var + 1e-5f);
  const size_t o = ((size_t)b * 784 + t) * 384 + c;
  qout[o]  = f2bf((acc - mu) * inv * g[c] + bb[c]);
  kvout[o] = f2bf(pool);
}

// ---------- Kernel 2: weights f32 -> bf16 ----------
__global__ __launch_bounds__(256) void k_wcvt(
    const float* __restrict__ a, const float* __restrict__ b,
    const float* __restrict__ c, const float* __restrict__ d,
    ushort_t* __restrict__ oa, ushort_t* __restrict__ ob,
    ushort_t* __restrict__ oc, ushort_t* __restrict__ od)
{
  const int i = blockIdx.x * 256 + threadIdx.x;
  if (i < 147456) {
    oa[i] = f2bf(a[i]); ob[i] = f2bf(b[i]);
    oc[i] = f2bf(c[i]); od[i] = f2bf(d[i]);
  }
}

// ---------- Kernel 3: full-res residual premix ------------------------------
// R[b,l,o,t] = b_fuse[o] + sum_c w_fuse[o,6+c]*bilinear(res_attn[b,c])(l,t)
// XCD-affine (b = blockIdx&7): per-XCD gather working set = res_attn(b) 3.7MB.
__global__ __launch_bounds__(256) void k_resmix(
    const float* __restrict__ ra, const float* __restrict__ w_fuse,
    const float* __restrict__ b_fuse, ushort_t* __restrict__ R)
{
  const int tid = threadIdx.x;
  const int b = blockIdx.x & 7, L = blockIdx.x >> 3;
  __shared__ float w2[36], bfu[6];
  if (tid < 36) w2[tid] = w_fuse[(tid / 6) * 12 + 6 + (tid % 6)];
  if (tid < 6)  bfu[tid] = b_fuse[tid];
  __syncthreads();

  const int Yc = L / 28, Xc = L % 28;
  const float cy = fminf(fmaxf((float)Yc * 0.5f - 0.25f, 0.f), 13.f);
  const float cx = fminf(fmaxf((float)Xc * 0.5f - 0.25f, 0.f), 13.f);
  const int y0 = (int)cy, y1 = min(y0 + 1, 13);
  const int x0 = (int)cx, x1 = min(x0 + 1, 13);
  const float fy = cy - (float)y0, fx = cx - (float)x0;
  const float w00 = (1.f - fy) * (1.f - fx), w01 = (1.f - fy) * fx;
  const float w10 = fy * (1.f - fx),         w11 = fy * fx;
  const int p00 = (y0 * 14 + x0) * 784, p01 = (y0 * 14 + x1) * 784;
  const int p10 = (y1 * 14 + x0) * 784, p11 = (y1 * 14 + x1) * 784;

  const float* rab = ra + (size_t)b * 6 * 153664;
  ushort_t* Rrow = R + ((size_t)(b * 784 + L) * 6) * 784;

  for (int t = tid; t < 784; t += 256) {
    float U[6];
    #pragma unroll
    for (int c = 0; c < 6; c++) {
      const float* rc = rab + (size_t)c * 153664;
      U[c] = w00 * rc[p00 + t] + w01 * rc[p01 + t]
           + w10 * rc[p10 + t] + w11 * rc[p11 + t];
    }
    #pragma unroll
    for (int o = 0; o < 6; o++) {
      float v = bfu[o];
      #pragma unroll
      for (int c = 0; c < 6; c++) v += w2[o * 6 + c] * U[c];
      Rrow[(size_t)o * 784 + t] = f2bf(v);
    }
  }
}

// ---------- Kernel 4: dense MFMA GEMM, Y[m,n]=X[m,:].W[n,:] -----------------
// MODE 0: bf16 row-major out; MODE 2: f32 + bias out.
template<int MODE>
__global__ __launch_bounds__(256) void k_gemm(
    const ushort_t* __restrict__ X, const ushort_t* __restrict__ W,
    const float* __restrict__ bias, void* __restrict__ Y)
{
  __shared__ ushort_t As[128][40];
  __shared__ ushort_t Bs[128][40];
  const int tid = threadIdx.x, w = tid >> 6, lane = tid & 63;
  const int quad = lane >> 4, r = lane & 15;
  const int m0 = blockIdx.y * 128, n0 = blockIdx.x * 128;
  const int wm = w >> 1, wn = w & 1;
  const int lr = tid >> 2, lc = (tid & 3) << 3;
  const ushort_t* xp = X + (size_t)(m0 + lr) * 384 + lc;
  const ushort_t* wp = W + (size_t)(n0 + lr) * 384 + lc;
  f32x4 acc[4][4] = {};
  for (int k0 = 0; k0 < 384; k0 += 32) {
    __syncthreads();
    *(uint4*)&As[lr][lc]      = *(const uint4*)(xp + k0);
    *(uint4*)&As[lr + 64][lc] = *(const uint4*)(xp + (size_t)64 * 384 + k0);
    *(uint4*)&Bs[lr][lc]      = *(const uint4*)(wp + k0);
    *(uint4*)&Bs[lr + 64][lc] = *(const uint4*)(wp + (size_t)64 * 384 + k0);
    __syncthreads();
    bf16x8 af[4], bf_[4];
    #pragma unroll
    for (int mt = 0; mt < 4; mt++) af[mt]  = *(const bf16x8*)&As[wm * 64 + mt * 16 + r][quad * 8];
    #pragma unroll
    for (int nt = 0; nt < 4; nt++) bf_[nt] = *(const bf16x8*)&Bs[wn * 64 + nt * 16 + r][quad * 8];
    #pragma unroll
    for (int mt = 0; mt < 4; mt++)
      #pragma unroll
      for (int nt = 0; nt < 4; nt++)
        acc[mt][nt] = __builtin_amdgcn_mfma_f32_16x16x32_bf16(af[mt], bf_[nt], acc[mt][nt], 0, 0, 0);
  }
  #pragma unroll
  for (int mt = 0; mt < 4; mt++) {
    #pragma unroll
    for (int nt = 0; nt < 4; nt++) {
      #pragma unroll
      for (int i = 0; i < 4; i++) {
        const int row = m0 + wm * 64 + mt * 16 + quad * 4 + i;
        const int col = n0 + wn * 64 + nt * 16 + r;
        const float v = acc[mt][nt][i];
        if constexpr (MODE == 2) ((float*)Y)[(size_t)row * 384 + col] = v + bias[col];
        else                     ((ushort_t*)Y)[(size_t)row * 384 + col] = f2bf(v);
      }
    }
  }
}

// ---------- Kernel 5: V GEMM with swapped roles: D = W.X^T ------------------
__global__ __launch_bounds__(256) void k_gemmT(
    const ushort_t* __restrict__ W, const ushort_t* __restrict__ X,
    ushort_t* __restrict__ Vt)
{
  __shared__ ushort_t As[128][40];
  __shared__ ushort_t Bs[128][40];
  const int tid = threadIdx.x, w = tid >> 6, lane = tid & 63;
  const int quad = lane >> 4, r = lane & 15;
  const int m0 = blockIdx.y * 128, n0 = blockIdx.x * 128;
  const int wm = w >> 1, wn = w & 1;
  const int lr = tid >> 2, lc = (tid & 3) << 3;
  const ushort_t* ap = W + (size_t)(m0 + lr) * 384 + lc;
  const ushort_t* bp = X + (size_t)(n0 + lr) * 384 + lc;
  f32x4 acc[4][4] = {};
  for (int k0 = 0; k0 < 384; k0 += 32) {
    __syncthreads();
    *(uint4*)&As[lr][lc]      = *(const uint4*)(ap + k0);
    *(uint4*)&As[lr + 64][lc] = *(const uint4*)(ap + (size_t)64 * 384 + k0);
    *(uint4*)&Bs[lr][lc]      = *(const uint4*)(bp + k0);
    *(uint4*)&Bs[lr + 64][lc] = *(const uint4*)(bp + (size_t)64 * 384 + k0);
    __syncthreads();
    bf16x8 af[4], bf_[4];
    #pragma unroll
    for (int mt = 0; mt < 4; mt++) af[mt]  = *(const bf16x8*)&As[wm * 64 + mt * 16 + r][quad * 8];
    #pragma unroll
    for (int nt = 0; nt < 4; nt++) bf_[nt] = *(const bf16x8*)&Bs[wn * 64 + nt * 16 + r][quad * 8];
    #pragma unroll
    for (int mt = 0; mt < 4; mt++)
      #pragma unroll
      for (int nt = 0; nt < 4; nt++)
        acc[mt][nt] = __builtin_amdgcn_mfma_f32_16x16x32_bf16(af[mt], bf_[nt], acc[mt][nt], 0, 0, 0);
  }
  #pragma unroll
  for (int mt = 0; mt < 4; mt++) {
    #pragma unroll
    for (int nt = 0; nt < 4; nt++) {
      #pragma unroll
      for (int i = 0; i < 4; i++) {
        const int d   = m0 + wm * 64 + mt * 16 + quad * 4 + i;
        const int tok = n0 + wn * 64 + nt * 16 + r;
        const int b = tok / 784, tt = tok % 784;
        Vt[((size_t)b * 384 + d) * 784 + tt] = f2bf(acc[mt][nt][i]);
      }
    }
  }
}

// ---------- Kernel 6: fused flash attention, NO t-split ---------------------
// 128 threads (2 waves) per (b, 8-row l-tile); grid 784 = all co-resident.
// 13 t-tiles, online softmax, writes final normalized bf16 O directly.
// MFMA uses m=16 with rows 8-15 garbage (masked at store) — MFMA is ~2% util.
// R loads for tile i are prefetched before phase A (hidden behind QK^T).
__global__ __launch_bounds__(128, 2) void k_fattn(
    const ushort_t* __restrict__ Qb, const ushort_t* __restrict__ Kb,
    const ushort_t* __restrict__ Vt, const ushort_t* __restrict__ R,
    const float* __restrict__ w_fuse, ushort_t* __restrict__ O)
{
  __shared__ ushort_t Ssc[6][16][72];   // 13824 B (rows 8-15 written, never read)
  __shared__ ushort_t Pl[6][16][72];    // 13824 B (rows 8-15 zeroed once)
  __shared__ float m_st[6][8], s_st[6][8];
  __shared__ float a_st[6][16];         // rows 8-15 stay 1.0
  __shared__ float w1[36];

  const int tid  = threadIdx.x;
  const int w    = tid >> 6, lane = tid & 63;
  const int quad = lane >> 4, r = lane & 15;
  const int b    = blockIdx.x & 7;          // XCD = linear%8 -> one batch/XCD
  const int m0   = (blockIdx.x >> 3) * 8;
  const float scale = 0.05103103630798288f; // 384^-0.5

  if (tid < 36) w1[tid] = w_fuse[(tid / 6) * 12 + (tid % 6)] * scale;
  if (tid < 48) { (&m_st[0][0])[tid] = -1e30f; (&s_st[0][0])[tid] = 0.f; }
  if (tid < 96) (&a_st[0][0])[tid] = 1.f;
  for (int i = tid; i < 864; i += 128) ((uint4*)Pl)[i] = uint4{0u, 0u, 0u, 0u};

  // persistent Q A-fragments (rows m0+r; r>=8 spill into next tile: discarded)
  const int lq = min(m0 + r, 783);
  const ushort_t* qrow = Qb + ((size_t)(b * 784 + lq)) * 384 + quad * 8;
  bf16x8 qf[6][2];
  #pragma unroll
  for (int h = 0; h < 6; h++) {
    qf[h][0] = ld_frag(qrow + h * 64);
    qf[h][1] = ld_frag(qrow + h * 64 + 32);
  }

  // phase-B mapping: l = tid>>4 (0..7), tq = tid&15 (4 t's at tq*4)
  const int bl_l = tid >> 4, tq = tid & 15;
  const ushort_t* Rrow = R + ((size_t)(b * 784 + m0 + bl_l) * 6) * 784;

  const size_t kbase  = (size_t)b * 784 * 384;
  const size_t vtbase = (size_t)b * 384 * 784;

  f32x4 oacc[6][2] = {};   // [head][d-subtile]; wave w owns d = o*64+(w*2+sub)*16

  for (int it = 0; it < 13; it++) {
    const int t0 = it * 64;

    // prefetch R for this tile (consumed in phase B, hidden behind phase A)
    const int t4 = t0 + tq * 4;
    uint2 rv[6];
    #pragma unroll
    for (int o = 0; o < 6; o++)
      rv[o] = *(const uint2*)(Rrow + (size_t)o * 784 + t4);

    // ---- phase A: QK^T, wave w covers t-half of 32 (2 subtiles) ----
    #pragma unroll
    for (int sub = 0; sub < 2; sub++) {
      const int tA = min(t0 + w * 32 + sub * 16 + r, 783);
      const ushort_t* krow = Kb + kbase + (size_t)tA * 384 + quad * 8;
      #pragma unroll
      for (int h = 0; h < 6; h++) {
        f32x4 sc = {};
        sc = __builtin_amdgcn_mfma_f32_16x16x32_bf16(qf[h][0], ld_frag(krow + h * 64),      sc, 0, 0, 0);
        sc = __builtin_amdgcn_mfma_f32_16x16x32_bf16(qf[h][1], ld_frag(krow + h * 64 + 32), sc, 0, 0, 0);
        #pragma unroll
        for (int i = 0; i < 4; i++)
          Ssc[h][quad * 4 + i][w * 32 + sub * 16 + r] = f2bf(sc[i]);
      }
    }
    __syncthreads();   // A done; also fences prior-iteration phase C (Pl reads)

    // ---- phase B: mix R + head-mix scores + online softmax ----
    {
      float F[6][4];
      #pragma unroll
      for (int o = 0; o < 6; o++) {
        F[o][0] = bflo(rv[o].x); F[o][1] = bfhi(rv[o].x);
        F[o][2] = bflo(rv[o].y); F[o][3] = bfhi(rv[o].y);
      }
      #pragma unroll
      for (int c = 0; c < 6; c++) {
        const uint2 sv = *(const uint2*)&Ssc[c][bl_l][tq * 4];
        const float s0 = bflo(sv.x), s1 = bfhi(sv.x);
        const float s2 = bflo(sv.y), s3 = bfhi(sv.y);
        #pragma unroll
        for (int o = 0; o < 6; o++) {
          const float wv = w1[o * 6 + c];
          F[o][0] += wv * s0; F[o][1] += wv * s1;
          F[o][2] += wv * s2; F[o][3] += wv * s3;
        }
      }
      #pragma unroll
      for (int j = 0; j < 4; j++) {
        if (t4 + j >= 784) {
          #pragma unroll
          for (int o = 0; o < 6; o++) F[o][j] = -1e30f;
        }
      }
      #pragma unroll
      for (int o = 0; o < 6; o++) {
        float mx = fmaxf(fmaxf(F[o][0], F[o][1]), fmaxf(F[o][2], F[o][3]));
        #pragma unroll
        for (int off = 8; off >= 1; off >>= 1) mx = fmaxf(mx, __shfl_xor(mx, off));
        const float m_old = m_st[o][bl_l];
        const float nm = fmaxf(m_old, mx);
        const float al = __expf(m_old - nm);
        float p0 = __expf(F[o][0] - nm), p1 = __expf(F[o][1] - nm);
        float p2 = __expf(F[o][2] - nm), p3 = __expf(F[o][3] - nm);
        float sm = p0 + p1 + p2 + p3;
        #pragma unroll
        for (int off = 8; off >= 1; off >>= 1) sm += __shfl_xor(sm, off);
        const uint lo = (uint)f2bf(p0) | ((uint)f2bf(p1) << 16);
        const uint hi = (uint)f2bf(p2) | ((uint)f2bf(p3) << 16);
        *(uint2*)&Pl[o][bl_l][tq * 4] = uint2{lo, hi};
        if (tq == 0) {
          m_st[o][bl_l] = nm;
          s_st[o][bl_l] = s_st[o][bl_l] * al + sm;
          a_st[o][bl_l] = al;
        }
      }
    }
    __syncthreads();

    // ---- phase C: O = O*alpha + P.V ; wave w owns d-subtiles (w*2, w*2+1) --
    #pragma unroll
    for (int o = 0; o < 6; o++) {
      const f32x4 al4 = *(const f32x4*)&a_st[o][quad * 4];
      const bf16x8 pa0 = *(const bf16x8*)&Pl[o][r][quad * 8];
      const bf16x8 pa1 = *(const bf16x8*)&Pl[o][r][quad * 8 + 32];
      #pragma unroll
      for (int sub = 0; sub < 2; sub++) {
        const int d = o * 64 + (w * 2 + sub) * 16 + r;
        const ushort_t* vrow = Vt + vtbase + (size_t)d * 784 + t0 + quad * 8;
        oacc[o][sub] *= al4;
        oacc[o][sub] = __builtin_amdgcn_mfma_f32_16x16x32_bf16(pa0, ld_frag(vrow),      oacc[o][sub], 0, 0, 0);
        oacc[o][sub] = __builtin_amdgcn_mfma_f32_16x16x32_bf16(pa1, ld_frag(vrow + 32), oacc[o][sub], 0, 0, 0);
      }
    }
  }

  // ---- epilogue: rows quad*4+i < 8 are valid; normalize and store bf16 ----
  if (quad < 2) {
    #pragma unroll
    for (int o = 0; o < 6; o++) {
      #pragma unroll
      for (int i = 0; i < 4; i++) {
        const int l = quad * 4 + i;
        const float inv = 1.f / s_st[o][l];
        const size_t rowbase = (size_t)(b * 784 + m0 + l) * 384;
        #pragma unroll
        for (int sub = 0; sub < 2; sub++)
          O[rowbase + o * 64 + (w * 2 + sub) * 16 + r] = f2bf(oacc[o][sub][i] * inv);
      }
    }
  }
}

// ---------- host launcher ----------
extern "C" void kernel_launch(void* const* d_in, const int* in_sizes, int n_in,
                              void* d_out, int out_size, void* d_ws, size_t ws_size,
                              hipStream_t stream)
{
  const float* x        = (const float*)d_in[0];
  const float* res_attn = (const float*)d_in[1];
  const float* conv_w   = (const float*)d_in[2];
  const float* ln_g     = (const float*)d_in[3];
  const float* ln_b     = (const float*)d_in[4];
  const float* wq       = (const float*)d_in[5];
  const float* wk       = (const float*)d_in[6];
  const float* wv       = (const float*)d_in[7];
  const float* w_proj   = (const float*)d_in[8];
  const float* b_proj   = (const float*)d_in[9];
  const float* w_fuse   = (const float*)d_in[10];
  const float* b_fuse   = (const float*)d_in[11];
  float* out = (float*)d_out;

  const size_t NE = (size_t)8 * 784 * 384;       // 2,408,448
  const size_t NW = 147456;
  const size_t NR = (size_t)8 * 784 * 6 * 784;   // 29,503,488
  ushort_t* q_ln_b = (ushort_t*)d_ws;
  ushort_t* kv_b   = q_ln_b + NE;
  ushort_t* Qb     = kv_b + NE;
  ushort_t* Kb     = Qb + NE;
  ushort_t* Vt     = Kb + NE;            // (b,384,784) + 64-elem pad
  ushort_t* Opre   = Vt + NE + 64;
  ushort_t* wqb    = Opre + NE;
  ushort_t* wkb    = wqb + NW;
  ushort_t* wvb    = wkb + NW;
  ushort_t* wpb    = wvb + NW;
  ushort_t* R      = wpb + NW;           // (b,784,6,784) bf16 + 64-elem pad

  k_prep  <<<dim3(8 * 784), dim3(384), 0, stream>>>(x, conv_w, ln_g, ln_b, q_ln_b, kv_b);
  k_wcvt  <<<dim3(576),     dim3(256), 0, stream>>>(wq, wk, wv, w_proj, wqb, wkb, wvb, wpb);
  k_resmix<<<dim3(8 * 784), dim3(256), 0, stream>>>(res_attn, w_fuse, b_fuse, R);

  k_gemm<0><<<dim3(3, 49), dim3(256), 0, stream>>>(q_ln_b, wqb, nullptr, Qb);
  k_gemm<0><<<dim3(3, 49), dim3(256), 0, stream>>>(kv_b,   wkb, nullptr, Kb);
  k_gemmT  <<<dim3(49, 3), dim3(256), 0, stream>>>(wvb, kv_b, Vt);

  k_fattn<<<dim3(784), dim3(128), 0, stream>>>(Qb, Kb, Vt, R, w_fuse, Opre);

  k_gemm<2><<<dim3(3, 49), dim3(256), 0, stream>>>(Opre, wpb, b_proj, out);
}